// Round 5
// baseline (2119.932 us; speedup 1.0000x reference)
//
#include <hip/hip_runtime.h>
#include <stdint.h>

// ResBlock: GraphConv(64->128) -> BN -> ReLU -> GraphConv(128->128) -> BN
//           + (x @ Wlin^T + blin) residual -> ReLU.
// Runtime dtype probe (bf16 vs f32). R4->R5: per-node CSR replaced by 64-node
// BUCKETS (NB~1563): LDS-hist -> 1-block scan -> bucket fill (padded cursors,
// L2-resident write window kills the 16x write amplification seen in k_fill).
// Aggregation = block-per-bucket scatter into LDS f32 accumulators (ds_add),
// coalesced row gathers, unrolled for MLP. Dense MFMA GEMMs unchanged from R4.

#define CIN 64
#define COUT 128
#define BN_EPS 1e-5f
#define CURPAD 16   // cursor padding (ints) -> spread atomic traffic across channels

typedef unsigned short u16;
typedef short short8 __attribute__((ext_vector_type(8)));
typedef float f32x4 __attribute__((ext_vector_type(4)));

__device__ __forceinline__ float bf2f(u16 u) {
    union { unsigned int i; float f; } v; v.i = ((unsigned int)u) << 16; return v.f;
}
__device__ __forceinline__ u16 f2bf(float f) {
    union { float f; unsigned int i; } v; v.f = f;
    unsigned int r = v.i + 0x7fffu + ((v.i >> 16) & 1u);  // RNE; finite inputs
    return (u16)(r >> 16);
}
__device__ __forceinline__ float lo16(unsigned int w) { return bf2f((u16)(w & 0xffffu)); }
__device__ __forceinline__ float hi16(unsigned int w) { return bf2f((u16)(w >> 16)); }

template<bool BF> __device__ __forceinline__ float ldf(const void* p, long i) {
    if (BF) return bf2f(((const u16*)p)[i]);
    return ((const float*)p)[i];
}
template<bool BF> __device__ __forceinline__ short8 ld8(const void* p, long i) {
    if (BF) return *(const short8*)((const u16*)p + i);
    const float* f = (const float*)p + i;
    short8 r;
#pragma unroll
    for (int j = 0; j < 8; ++j) r[j] = (short)f2bf(f[j]);
    return r;
}

// ---- coalesced 64-row chunk staging into padded LDS (bf16 in LDS) --------
template<bool BF, int RL>
__device__ __forceinline__ void stage_tile(const void* g, long first_row,
                                           u16* lds, int stride, int col_off,
                                           int n, int tid) {
    if (BF) {
        const int SPR = RL / 8;
        const int NPT = 64 * SPR / 256;
#pragma unroll
        for (int i = 0; i < NPT; ++i) {
            int s = tid + i * 256;
            int row = s / SPR, within = s % SPR;
            long rg = first_row + row; if (rg > n - 1) rg = n - 1;
            short8 v = *(const short8*)((const u16*)g + rg * RL + within * 8);
            *(short8*)(lds + row * stride + col_off + within * 8) = v;
        }
    } else {
        const int SPR = RL / 4;
        const int NPT = 64 * SPR / 256;
#pragma unroll
        for (int i = 0; i < NPT; ++i) {
            int s = tid + i * 256;
            int row = s / SPR, within = s % SPR;
            long rg = first_row + row; if (rg > n - 1) rg = n - 1;
            float4 v = *(const float4*)((const float*)g + rg * RL + within * 4);
            u16* d = lds + row * stride + col_off + within * 4;
            d[0] = f2bf(v.x); d[1] = f2bf(v.y); d[2] = f2bf(v.z); d[3] = f2bf(v.w);
        }
    }
}

// stage y0 (bf16) with fused BN0-apply + ReLU
__device__ __forceinline__ void stage_y0p(const u16* y0, long first_row,
                                          u16* lds, int stride,
                                          const float* __restrict__ sc,
                                          const float* __restrict__ sh,
                                          int n, int tid) {
#pragma unroll
    for (int i = 0; i < 4; ++i) {
        int s = tid + i * 256;
        int row = s >> 4, within = s & 15;
        long rg = first_row + row; if (rg > n - 1) rg = n - 1;
        short8 v = *(const short8*)(y0 + rg * COUT + within * 8);
        int c = within * 8;
        short8 o;
#pragma unroll
        for (int j = 0; j < 8; ++j)
            o[j] = (short)f2bf(fmaxf(bf2f((u16)v[j]) * sc[c + j] + sh[c + j], 0.f));
        *(short8*)(lds + row * stride + within * 8) = o;
    }
}

// ---------------- dtype detection ----------------
__global__ void k_detect(const unsigned int* __restrict__ x, int* __restrict__ flag) {
    int lane = threadIdx.x;  // 64
    int cnt = 0;
#pragma unroll
    for (int i = 0; i < 8; ++i) {
        unsigned int w = x[lane * 8 + i];
        unsigned int e0 = (w >> 7) & 0xFFu, e1 = (w >> 23) & 0xFFu;
        cnt += (e0 >= 0x60u && e0 <= 0x8Eu);
        cnt += (e1 >= 0x60u && e1 <= 0x8Eu);
    }
    for (int o = 32; o; o >>= 1) cnt += __shfl_down(cnt, o);
    if (lane == 0) *flag = (cnt > 850) ? 1 : 0;   // 1 => bf16
}

// ---------------- bucket build (bucket = dst >> 6) ----------------
__global__ __launch_bounds__(256) void k_bhist(const int* __restrict__ dst,
                                               int* __restrict__ bcount, int E, int nb) {
    __shared__ int h[2048];
    for (int i = threadIdx.x; i < nb; i += 256) h[i] = 0;
    __syncthreads();
    int stride = gridDim.x * 256;
    for (int e = blockIdx.x * 256 + threadIdx.x; e < E; e += stride)
        atomicAdd(&h[dst[e] >> 6], 1);
    __syncthreads();
    for (int i = threadIdx.x; i < nb; i += 256)
        if (h[i]) atomicAdd(&bcount[i], h[i]);
}

__global__ void k_bscan(const int* __restrict__ bcount, int* __restrict__ bstart,
                        int* __restrict__ bcursor, int nb, int E) {
    __shared__ int s[2048];
    int t = threadIdx.x;                 // 1024 threads
    s[t]        = (t < nb) ? bcount[t] : 0;
    s[t + 1024] = (t + 1024 < nb) ? bcount[t + 1024] : 0;
    __syncthreads();
    for (int o = 1; o < 2048; o <<= 1) {
        int a = (t >= o) ? s[t - o] : 0;
        int b = (t + 1024 >= o) ? s[t + 1024 - o] : 0;
        __syncthreads();
        s[t] += a; s[t + 1024] += b;
        __syncthreads();
    }
    if (t < nb) {
        int ex = s[t] - bcount[t];
        bstart[t] = ex; bcursor[t * CURPAD] = ex;
    }
    int t2 = t + 1024;
    if (t2 < nb) {
        int ex = s[t2] - bcount[t2];
        bstart[t2] = ex; bcursor[t2 * CURPAD] = ex;
    }
    if (t == 0) bstart[nb] = E;
}

// rec = (dst&63)<<20 | src  (src < 2^20; N=100000 ok)
__global__ __launch_bounds__(256) void k_bfill(const int* __restrict__ src,
        const int* __restrict__ dst, int* __restrict__ bcursor,
        unsigned int* __restrict__ barr, int E) {
    int e = blockIdx.x * 256 + threadIdx.x;
    if (e < E) {
        int d = dst[e];
        unsigned int rec = ((unsigned int)(d & 63) << 20) | (unsigned int)src[e];
        int pos = atomicAdd(&bcursor[(d >> 6) * CURPAD], 1);
        barr[pos] = rec;
    }
}

// ---------------- bucket aggregation: scatter into LDS ----------------
// agg0: x rows 64 cols. Quarter-wave per edge (16 lanes x 2 u32-cols x2).
template<bool BF>
__device__ __forceinline__ void agg0b_impl(const void* x, const unsigned int* barr,
                                           const int* bstart, u16* agg, int n, float* acc) {
    const int ST = 65;  // pad: rotate banks by low%32
    int tid = threadIdx.x;
    for (int i = tid; i < 64 * ST; i += 256) acc[i] = 0.f;
    __syncthreads();
    int b = blockIdx.x, nb0 = b << 6;
    int e0 = bstart[b], e1 = bstart[b + 1];
    int qid = tid >> 4, l4 = tid & 15;

    int t = e0 + qid;
    for (; t + 16 < e1; t += 32) {   // unroll x2 for MLP
        unsigned int rec0 = barr[t], rec1 = barr[t + 16];
        int s0 = rec0 & 0xFFFFF, w0i = rec0 >> 20;
        int s1 = rec1 & 0xFFFFF, w1i = rec1 >> 20;
        float a0, a1, a2, a3, b0, b1, b2, b3;
        if (BF) {
            unsigned int wa0 = ((const unsigned int*)x)[(long)s0 * 32 + l4];
            unsigned int wb0 = ((const unsigned int*)x)[(long)s0 * 32 + 16 + l4];
            unsigned int wa1 = ((const unsigned int*)x)[(long)s1 * 32 + l4];
            unsigned int wb1 = ((const unsigned int*)x)[(long)s1 * 32 + 16 + l4];
            a0 = lo16(wa0); a1 = hi16(wa0); a2 = lo16(wb0); a3 = hi16(wb0);
            b0 = lo16(wa1); b1 = hi16(wa1); b2 = lo16(wb1); b3 = hi16(wb1);
        } else {
            float2 wa0 = ((const float2*)x)[(long)s0 * 32 + l4];
            float2 wb0 = ((const float2*)x)[(long)s0 * 32 + 16 + l4];
            float2 wa1 = ((const float2*)x)[(long)s1 * 32 + l4];
            float2 wb1 = ((const float2*)x)[(long)s1 * 32 + 16 + l4];
            a0 = wa0.x; a1 = wa0.y; a2 = wb0.x; a3 = wb0.y;
            b0 = wa1.x; b1 = wa1.y; b2 = wb1.x; b3 = wb1.y;
        }
        float* r0 = acc + w0i * ST;
        float* r1 = acc + w1i * ST;
        atomicAdd(&r0[2 * l4], a0);      atomicAdd(&r0[2 * l4 + 1], a1);
        atomicAdd(&r0[32 + 2 * l4], a2); atomicAdd(&r0[32 + 2 * l4 + 1], a3);
        atomicAdd(&r1[2 * l4], b0);      atomicAdd(&r1[2 * l4 + 1], b1);
        atomicAdd(&r1[32 + 2 * l4], b2); atomicAdd(&r1[32 + 2 * l4 + 1], b3);
    }
    for (; t < e1; t += 16) {
        unsigned int rec = barr[t];
        int s0 = rec & 0xFFFFF, low = rec >> 20;
        float a0, a1, a2, a3;
        if (BF) {
            unsigned int wa = ((const unsigned int*)x)[(long)s0 * 32 + l4];
            unsigned int wb = ((const unsigned int*)x)[(long)s0 * 32 + 16 + l4];
            a0 = lo16(wa); a1 = hi16(wa); a2 = lo16(wb); a3 = hi16(wb);
        } else {
            float2 wa = ((const float2*)x)[(long)s0 * 32 + l4];
            float2 wb = ((const float2*)x)[(long)s0 * 32 + 16 + l4];
            a0 = wa.x; a1 = wa.y; a2 = wb.x; a3 = wb.y;
        }
        float* r = acc + low * ST;
        atomicAdd(&r[2 * l4], a0);      atomicAdd(&r[2 * l4 + 1], a1);
        atomicAdd(&r[32 + 2 * l4], a2); atomicAdd(&r[32 + 2 * l4 + 1], a3);
    }
    __syncthreads();
    int row = tid >> 2, cg = (tid & 3) * 16;
    int node = nb0 + row;
    if (node < n) {
        unsigned int* d = (unsigned int*)agg + (long)node * 32 + cg / 2;
        const float* r = acc + row * ST + cg;
#pragma unroll
        for (int j = 0; j < 8; ++j)
            d[j] = (unsigned int)f2bf(r[2 * j]) | ((unsigned int)f2bf(r[2 * j + 1]) << 16);
    }
}

__global__ __launch_bounds__(256) void k_agg0b(const int* __restrict__ flag,
        const void* x, const unsigned int* __restrict__ barr,
        const int* __restrict__ bstart, u16* __restrict__ agg, int n) {
    __shared__ float acc[64 * 65];
    if (*flag) agg0b_impl<true >(x, barr, bstart, agg, n, acc);
    else       agg0b_impl<false>(x, barr, bstart, agg, n, acc);
}

// agg1: gathers relu(bn0(y0_raw)) rows (128 cols, always bf16 internal).
// Half-wave per edge; unroll x4 for MLP.
__global__ __launch_bounds__(256) void k_agg1b(const u16* __restrict__ y0,
        const unsigned int* __restrict__ barr, const int* __restrict__ bstart,
        const float* __restrict__ sc, const float* __restrict__ sh,
        u16* __restrict__ agg, int n) {
    const int ST = 131;
    __shared__ float acc[64 * ST];
    int tid = threadIdx.x;
    for (int i = tid; i < 64 * ST; i += 256) acc[i] = 0.f;
    __syncthreads();
    int b = blockIdx.x, nb0 = b << 6;
    int e0 = bstart[b], e1 = bstart[b + 1];
    int hid = tid >> 5, l = tid & 31;
    float s0 = sc[2 * l], s1 = sc[2 * l + 1], s2 = sc[64 + 2 * l], s3 = sc[65 + 2 * l];
    float h0 = sh[2 * l], h1 = sh[2 * l + 1], h2 = sh[64 + 2 * l], h3 = sh[65 + 2 * l];
    const unsigned int* y32 = (const unsigned int*)y0;

    int t = e0 + hid;
    for (; t + 24 < e1; t += 32) {   // unroll x4
        unsigned int rc[4]; int sr[4], lw[4];
        unsigned int wa[4], wb[4];
#pragma unroll
        for (int k = 0; k < 4; ++k) rc[k] = barr[t + 8 * k];
#pragma unroll
        for (int k = 0; k < 4; ++k) { sr[k] = rc[k] & 0xFFFFF; lw[k] = rc[k] >> 20; }
#pragma unroll
        for (int k = 0; k < 4; ++k) {
            wa[k] = y32[(long)sr[k] * 64 + l];
            wb[k] = y32[(long)sr[k] * 64 + 32 + l];
        }
#pragma unroll
        for (int k = 0; k < 4; ++k) {
            float* r = acc + lw[k] * ST;
            atomicAdd(&r[2 * l],          fmaxf(lo16(wa[k]) * s0 + h0, 0.f));
            atomicAdd(&r[2 * l + 1],      fmaxf(hi16(wa[k]) * s1 + h1, 0.f));
            atomicAdd(&r[64 + 2 * l],     fmaxf(lo16(wb[k]) * s2 + h2, 0.f));
            atomicAdd(&r[64 + 2 * l + 1], fmaxf(hi16(wb[k]) * s3 + h3, 0.f));
        }
    }
    for (; t < e1; t += 8) {
        unsigned int rec = barr[t];
        int src = rec & 0xFFFFF, low = rec >> 20;
        unsigned int wa = y32[(long)src * 64 + l];
        unsigned int wb = y32[(long)src * 64 + 32 + l];
        float* r = acc + low * ST;
        atomicAdd(&r[2 * l],          fmaxf(lo16(wa) * s0 + h0, 0.f));
        atomicAdd(&r[2 * l + 1],      fmaxf(hi16(wa) * s1 + h1, 0.f));
        atomicAdd(&r[64 + 2 * l],     fmaxf(lo16(wb) * s2 + h2, 0.f));
        atomicAdd(&r[64 + 2 * l + 1], fmaxf(hi16(wb) * s3 + h3, 0.f));
    }
    __syncthreads();
    int row = tid >> 2, cg = (tid & 3) * 32;
    int node = nb0 + row;
    if (node < n) {
        unsigned int* d = (unsigned int*)agg + (long)node * 64 + cg / 2;
        const float* r = acc + row * ST + cg;
#pragma unroll
        for (int j = 0; j < 16; ++j)
            d[j] = (unsigned int)f2bf(r[2 * j]) | ((unsigned int)f2bf(r[2 * j + 1]) << 16);
    }
}

// ---------------- GEMM0: y0 = [x|agg0] @ [Wr0;Wn0]^T, fused stats ----------
template<bool BF>
__device__ __forceinline__ void gemm0_impl(const void* x, const u16* agg,
                                           const void* Wr, const void* Wn,
                                           u16* y0, float* sum, float* sumsq,
                                           int n, u16* lds) {
    const int ST = 130;
    int tid = threadIdx.x;
    int wave = tid >> 6, lane = tid & 63, lr = lane & 15, q = lane >> 4;
    long chunk0 = (long)blockIdx.x * 64;

    short8 wf[2][4];
#pragma unroll
    for (int i = 0; i < 2; ++i) {
        int c = (2 * wave + i) * 16 + lr;
#pragma unroll
        for (int ks = 0; ks < 4; ++ks) {
            const void* W = (ks < 2) ? Wr : Wn;
            wf[i][ks] = ld8<BF>(W, (long)c * CIN + (ks & 1) * 32 + q * 8);
        }
    }
    stage_tile<BF, 64>(x, chunk0, lds, ST, 0, n, tid);
    stage_tile<true, 64>(agg, chunk0, lds, ST, 64, n, tid);
    __syncthreads();

    float st[2] = {0.f, 0.f}, sq[2] = {0.f, 0.f};
#pragma unroll
    for (int t = 0; t < 4; ++t) {
        short8 a[4];
#pragma unroll
        for (int ks = 0; ks < 4; ++ks)
            a[ks] = *(const short8*)(lds + (t * 16 + lr) * ST + ks * 32 + q * 8);
#pragma unroll
        for (int i = 0; i < 2; ++i) {
            f32x4 acc = {0.f, 0.f, 0.f, 0.f};
#pragma unroll
            for (int ks = 0; ks < 4; ++ks)
                acc = __builtin_amdgcn_mfma_f32_16x16x32_bf16(a[ks], wf[i][ks], acc, 0, 0, 0);
            int c = (2 * wave + i) * 16 + lr;
#pragma unroll
            for (int r = 0; r < 4; ++r) {
                long row = chunk0 + t * 16 + q * 4 + r;
                if (row < n) {
                    y0[row * COUT + c] = f2bf(acc[r]);   // b0 cancels in BN
                    st[i] += acc[r]; sq[i] += acc[r] * acc[r];
                }
            }
        }
    }
#pragma unroll
    for (int i = 0; i < 2; ++i) {
        st[i] += __shfl_xor(st[i], 16); st[i] += __shfl_xor(st[i], 32);
        sq[i] += __shfl_xor(sq[i], 16); sq[i] += __shfl_xor(sq[i], 32);
    }
    if (q == 0) {
#pragma unroll
        for (int i = 0; i < 2; ++i) {
            int c = (2 * wave + i) * 16 + lr;
            atomicAdd(&sum[c], st[i]);
            atomicAdd(&sumsq[c], sq[i]);
        }
    }
}

__global__ __launch_bounds__(256) void k_gemm0(const int* __restrict__ flag,
        const void* x, const u16* __restrict__ agg, const void* Wr, const void* Wn,
        u16* __restrict__ y0, float* __restrict__ sum, float* __restrict__ sumsq, int n) {
    __shared__ u16 lds[64 * 130];
    if (*flag) gemm0_impl<true >(x, agg, Wr, Wn, y0, sum, sumsq, n, lds);
    else       gemm0_impl<false>(x, agg, Wr, Wn, y0, sum, sumsq, n, lds);
}

// ---------------- GEMM1: y1 = [relu(bn0(y0))|agg1] @ [Wr1;Wn1]^T, stats ----
template<bool BF>
__device__ __forceinline__ void gemm1_impl(const u16* y0, const u16* agg,
                                           const void* Wr, const void* Wn,
                                           const float* sc0, const float* sh0,
                                           u16* y1, float* sum, float* sumsq,
                                           int n, u16* lds) {
    const int ST = 258;
    int tid = threadIdx.x;
    int wave = tid >> 6, lane = tid & 63, lr = lane & 15, q = lane >> 4;
    long chunk0 = (long)blockIdx.x * 64;

    short8 wf[2][8];
#pragma unroll
    for (int i = 0; i < 2; ++i) {
        int c = (2 * wave + i) * 16 + lr;
#pragma unroll
        for (int ks = 0; ks < 8; ++ks) {
            const void* W = (ks < 4) ? Wr : Wn;
            wf[i][ks] = ld8<BF>(W, (long)c * COUT + (ks & 3) * 32 + q * 8);
        }
    }
    stage_y0p(y0, chunk0, lds, ST, sc0, sh0, n, tid);
    stage_tile<true, 128>(agg, chunk0, lds, ST, 128, n, tid);
    __syncthreads();

    float st[2] = {0.f, 0.f}, sq[2] = {0.f, 0.f};
#pragma unroll
    for (int t = 0; t < 4; ++t) {
        short8 a[8];
#pragma unroll
        for (int ks = 0; ks < 8; ++ks)
            a[ks] = *(const short8*)(lds + (t * 16 + lr) * ST + ks * 32 + q * 8);
#pragma unroll
        for (int i = 0; i < 2; ++i) {
            f32x4 acc = {0.f, 0.f, 0.f, 0.f};
#pragma unroll
            for (int ks = 0; ks < 8; ++ks)
                acc = __builtin_amdgcn_mfma_f32_16x16x32_bf16(a[ks], wf[i][ks], acc, 0, 0, 0);
            int c = (2 * wave + i) * 16 + lr;
#pragma unroll
            for (int r = 0; r < 4; ++r) {
                long row = chunk0 + t * 16 + q * 4 + r;
                if (row < n) {
                    y1[row * COUT + c] = f2bf(acc[r]);   // b1 cancels in BN
                    st[i] += acc[r]; sq[i] += acc[r] * acc[r];
                }
            }
        }
    }
#pragma unroll
    for (int i = 0; i < 2; ++i) {
        st[i] += __shfl_xor(st[i], 16); st[i] += __shfl_xor(st[i], 32);
        sq[i] += __shfl_xor(sq[i], 16); sq[i] += __shfl_xor(sq[i], 32);
    }
    if (q == 0) {
#pragma unroll
        for (int i = 0; i < 2; ++i) {
            int c = (2 * wave + i) * 16 + lr;
            atomicAdd(&sum[c], st[i]);
            atomicAdd(&sumsq[c], sq[i]);
        }
    }
}

__global__ __launch_bounds__(256) void k_gemm1(const int* __restrict__ flag,
        const u16* __restrict__ y0, const u16* __restrict__ agg,
        const void* Wr, const void* Wn,
        const float* __restrict__ sc0, const float* __restrict__ sh0,
        u16* y1_bf /*=d_out*/, u16* y1_ws,
        float* __restrict__ sum, float* __restrict__ sumsq, int n) {
    __shared__ u16 lds[64 * 258];
    u16* y1 = *flag ? y1_bf : y1_ws;
    if (*flag) gemm1_impl<true >(y0, agg, Wr, Wn, sc0, sh0, y1, sum, sumsq, n, lds);
    else       gemm1_impl<false>(y0, agg, Wr, Wn, sc0, sh0, y1, sum, sumsq, n, lds);
}

// ---------------- BN finalize ----------------
__global__ void k_bnfin(const int* __restrict__ flag,
                        const float* __restrict__ sum, const float* __restrict__ sumsq,
                        const void* g, const void* be,
                        float* __restrict__ scale, float* __restrict__ shift, int n) {
    int c = threadIdx.x;
    bool bf = (*flag != 0);
    float inv = 1.f / (float)n;
    float mu = sum[c] * inv;
    float var = fmaxf(sumsq[c] * inv - mu * mu, 0.f);
    float gv = bf ? bf2f(((const u16*)g)[c]) : ((const float*)g)[c];
    float bv = bf ? bf2f(((const u16*)be)[c]) : ((const float*)be)[c];
    float sc = gv * rsqrtf(var + BN_EPS);
    scale[c] = sc;
    shift[c] = bv - mu * sc;
}

// ---------------- final: out = relu(bn1(y1) + x@Wlin^T + blin) ------------
template<bool BF>
__device__ __forceinline__ void final_impl(const void* x, const u16* y1,
                                           const void* Wlin, const void* blin,
                                           const float* sc, const float* sh,
                                           void* out, int n, u16* lds) {
    const int ST = 194;
    int tid = threadIdx.x;
    int wave = tid >> 6, lane = tid & 63, lr = lane & 15, q = lane >> 4;
    long chunk0 = (long)blockIdx.x * 64;

    short8 wf[2][2];
    float blc[2], scc[2], shc[2];
#pragma unroll
    for (int i = 0; i < 2; ++i) {
        int c = (2 * wave + i) * 16 + lr;
#pragma unroll
        for (int ks = 0; ks < 2; ++ks)
            wf[i][ks] = ld8<BF>(Wlin, (long)c * CIN + ks * 32 + q * 8);
        blc[i] = ldf<BF>(blin, c);
        scc[i] = sc[c]; shc[i] = sh[c];
    }
    stage_tile<BF, 64>(x, chunk0, lds, ST, 0, n, tid);
    stage_tile<true, 128>(y1, chunk0, lds, ST, 64, n, tid);
    __syncthreads();

#pragma unroll
    for (int t = 0; t < 4; ++t) {
        short8 a[2];
#pragma unroll
        for (int ks = 0; ks < 2; ++ks)
            a[ks] = *(const short8*)(lds + (t * 16 + lr) * ST + ks * 32 + q * 8);
#pragma unroll
        for (int i = 0; i < 2; ++i) {
            f32x4 acc = {0.f, 0.f, 0.f, 0.f};
            acc = __builtin_amdgcn_mfma_f32_16x16x32_bf16(a[0], wf[i][0], acc, 0, 0, 0);
            acc = __builtin_amdgcn_mfma_f32_16x16x32_bf16(a[1], wf[i][1], acc, 0, 0, 0);
            int c = (2 * wave + i) * 16 + lr;
#pragma unroll
            for (int r = 0; r < 4; ++r) {
                long row = chunk0 + t * 16 + q * 4 + r;
                if (row < n) {
                    float yv = bf2f(lds[(t * 16 + q * 4 + r) * ST + 64 + c]);
                    float v = acc[r] + blc[i] + yv * scc[i] + shc[i];
                    v = fmaxf(v, 0.f);
                    if (BF) ((u16*)out)[row * COUT + c] = f2bf(v);
                    else    ((float*)out)[row * COUT + c] = v;
                }
            }
        }
    }
}

__global__ __launch_bounds__(256) void k_final(const int* __restrict__ flag,
        const void* x, const void* Wlin, const void* blin,
        const u16* y1_bf /*=d_out*/, const u16* y1_ws,
        const float* __restrict__ sc, const float* __restrict__ sh,
        void* out, int n) {
    __shared__ u16 lds[64 * 194];
    const u16* y1 = *flag ? y1_bf : y1_ws;
    if (*flag) final_impl<true >(x, y1, Wlin, blin, sc, sh, out, n, lds);
    else       final_impl<false>(x, y1, Wlin, blin, sc, sh, out, n, lds);
}

extern "C" void kernel_launch(void* const* d_in, const int* in_sizes, int n_in,
                              void* d_out, int out_size, void* d_ws, size_t ws_size,
                              hipStream_t stream) {
    (void)n_in; (void)out_size; (void)ws_size;
    const void* x    = d_in[0];
    const int*  ei   = (const int*)d_in[1];
    const void* Wr0  = d_in[2];
    const void* Wn0  = d_in[3];
    /* b0 dropped: BN-invariant */
    const void* g0   = d_in[5];
    const void* be0  = d_in[6];
    const void* Wr1  = d_in[7];
    const void* Wn1  = d_in[8];
    /* b1 dropped */
    const void* g1   = d_in[10];
    const void* be1  = d_in[11];
    const void* Wlin = d_in[12];
    const void* blin = d_in[13];

    const int N = in_sizes[0] / CIN;
    const int E = in_sizes[1] / 2;
    const int* src = ei;
    const int* dst = ei + E;
    const int NB = (N + 63) >> 6;   // 64-node buckets; NB <= 2048 for N <= 131072

    // ---- workspace carve (256B aligned); f32-only region LAST ----
    char* base = (char*)d_ws;
    size_t off = 0;
    auto carve = [&](size_t bytes) -> void* {
        void* p = base + off;
        off = (off + bytes + 255) & ~(size_t)255;
        return p;
    };
    int*   flag    = (int*)carve(256);
    int*   bcount  = (int*)carve(2048 * sizeof(int));
    int*   bstart  = (int*)carve(2049 * sizeof(int));
    int*   bcursor = (int*)carve(2048 * CURPAD * sizeof(int));  // padded cursors
    float* stats   = (float*)carve(512 * sizeof(float));  // sum0,sq0,sum1,sq1
    float* scsh    = (float*)carve(512 * sizeof(float));  // scale0,shift0,scale1,shift1
    unsigned int* barr = (unsigned int*)carve((size_t)E * sizeof(int));
    u16*   aggu    = (u16*)carve((size_t)N * COUT * sizeof(u16)); // agg0 aliases agg1
    u16*   y0      = (u16*)carve((size_t)N * COUT * sizeof(u16));
    u16*   y1_ws   = (u16*)carve((size_t)N * COUT * sizeof(u16)); // f32 mode only

    hipMemsetAsync(bcount, 0, 2048 * sizeof(int), stream);
    hipMemsetAsync(stats, 0, 512 * sizeof(float), stream);

    const int eb  = (E + 255) / 256;
    const int nch = (N + 63) / 64;

    k_detect<<<1, 64, 0, stream>>>((const unsigned int*)x, flag);

    k_bhist<<<256, 256, 0, stream>>>(dst, bcount, E, NB);
    k_bscan<<<1, 1024, 0, stream>>>(bcount, bstart, bcursor, NB, E);
    k_bfill<<<eb, 256, 0, stream>>>(src, dst, bcursor, barr, E);

    k_agg0b<<<NB, 256, 0, stream>>>(flag, x, barr, bstart, aggu, N);
    k_gemm0<<<nch, 256, 0, stream>>>(flag, x, aggu, Wr0, Wn0, y0,
                                     stats, stats + 128, N);
    k_bnfin<<<1, 128, 0, stream>>>(flag, stats, stats + 128, g0, be0,
                                   scsh, scsh + 128, N);

    k_agg1b<<<NB, 256, 0, stream>>>(y0, barr, bstart, scsh, scsh + 128, aggu, N);
    k_gemm1<<<nch, 256, 0, stream>>>(flag, y0, aggu, Wr1, Wn1, scsh, scsh + 128,
                                     (u16*)d_out, y1_ws, stats + 256, stats + 384, N);
    k_bnfin<<<1, 128, 0, stream>>>(flag, stats + 256, stats + 384, g1, be1,
                                   scsh + 256, scsh + 384, N);

    k_final<<<nch, 256, 0, stream>>>(flag, x, Wlin, blin,
                                     (const u16*)d_out, y1_ws,
                                     scsh + 256, scsh + 384, d_out, N);
}

// Round 6
// 509.230 us; speedup vs baseline: 4.1630x; 4.1630x over previous
//
#include <hip/hip_runtime.h>
#include <stdint.h>

// ResBlock: GraphConv(64->128) -> BN -> ReLU -> GraphConv(128->128) -> BN
//           + (x @ Wlin^T + blin) residual -> ReLU.
// Runtime dtype probe (bf16 vs f32).
// R5->R6: LDS scatter-atomic aggregation REVERTED (205M same-address ds_adds
// = 1181us). Kept: bucket edge build (no write amp). Added: per-bucket
// counting sort -> node-sorted CSR (contiguous 4KB write window per block).
// Aggregation = R4 pull-mode (wave/node, register acc, coalesced row loads).

#define CIN 64
#define COUT 128
#define BN_EPS 1e-5f
#define CURPAD 16

typedef unsigned short u16;
typedef short short8 __attribute__((ext_vector_type(8)));
typedef float f32x4 __attribute__((ext_vector_type(4)));

__device__ __forceinline__ float bf2f(u16 u) {
    union { unsigned int i; float f; } v; v.i = ((unsigned int)u) << 16; return v.f;
}
__device__ __forceinline__ u16 f2bf(float f) {
    union { float f; unsigned int i; } v; v.f = f;
    unsigned int r = v.i + 0x7fffu + ((v.i >> 16) & 1u);  // RNE; finite inputs
    return (u16)(r >> 16);
}
__device__ __forceinline__ float lo16(unsigned int w) { return bf2f((u16)(w & 0xffffu)); }
__device__ __forceinline__ float hi16(unsigned int w) { return bf2f((u16)(w >> 16)); }

template<bool BF> __device__ __forceinline__ float ldf(const void* p, long i) {
    if (BF) return bf2f(((const u16*)p)[i]);
    return ((const float*)p)[i];
}
template<bool BF> __device__ __forceinline__ short8 ld8(const void* p, long i) {
    if (BF) return *(const short8*)((const u16*)p + i);
    const float* f = (const float*)p + i;
    short8 r;
#pragma unroll
    for (int j = 0; j < 8; ++j) r[j] = (short)f2bf(f[j]);
    return r;
}

// ---- coalesced 64-row chunk staging into padded LDS (bf16 in LDS) --------
template<bool BF, int RL>
__device__ __forceinline__ void stage_tile(const void* g, long first_row,
                                           u16* lds, int stride, int col_off,
                                           int n, int tid) {
    if (BF) {
        const int SPR = RL / 8;
        const int NPT = 64 * SPR / 256;
#pragma unroll
        for (int i = 0; i < NPT; ++i) {
            int s = tid + i * 256;
            int row = s / SPR, within = s % SPR;
            long rg = first_row + row; if (rg > n - 1) rg = n - 1;
            short8 v = *(const short8*)((const u16*)g + rg * RL + within * 8);
            *(short8*)(lds + row * stride + col_off + within * 8) = v;
        }
    } else {
        const int SPR = RL / 4;
        const int NPT = 64 * SPR / 256;
#pragma unroll
        for (int i = 0; i < NPT; ++i) {
            int s = tid + i * 256;
            int row = s / SPR, within = s % SPR;
            long rg = first_row + row; if (rg > n - 1) rg = n - 1;
            float4 v = *(const float4*)((const float*)g + rg * RL + within * 4);
            u16* d = lds + row * stride + col_off + within * 4;
            d[0] = f2bf(v.x); d[1] = f2bf(v.y); d[2] = f2bf(v.z); d[3] = f2bf(v.w);
        }
    }
}

// stage y0 (bf16) with fused BN0-apply + ReLU
__device__ __forceinline__ void stage_y0p(const u16* y0, long first_row,
                                          u16* lds, int stride,
                                          const float* __restrict__ sc,
                                          const float* __restrict__ sh,
                                          int n, int tid) {
#pragma unroll
    for (int i = 0; i < 4; ++i) {
        int s = tid + i * 256;
        int row = s >> 4, within = s & 15;
        long rg = first_row + row; if (rg > n - 1) rg = n - 1;
        short8 v = *(const short8*)(y0 + rg * COUT + within * 8);
        int c = within * 8;
        short8 o;
#pragma unroll
        for (int j = 0; j < 8; ++j)
            o[j] = (short)f2bf(fmaxf(bf2f((u16)v[j]) * sc[c + j] + sh[c + j], 0.f));
        *(short8*)(lds + row * stride + within * 8) = o;
    }
}

// ---------------- dtype detection ----------------
__global__ void k_detect(const unsigned int* __restrict__ x, int* __restrict__ flag) {
    int lane = threadIdx.x;  // 64
    int cnt = 0;
#pragma unroll
    for (int i = 0; i < 8; ++i) {
        unsigned int w = x[lane * 8 + i];
        unsigned int e0 = (w >> 7) & 0xFFu, e1 = (w >> 23) & 0xFFu;
        cnt += (e0 >= 0x60u && e0 <= 0x8Eu);
        cnt += (e1 >= 0x60u && e1 <= 0x8Eu);
    }
    for (int o = 32; o; o >>= 1) cnt += __shfl_down(cnt, o);
    if (lane == 0) *flag = (cnt > 850) ? 1 : 0;   // 1 => bf16
}

// ---------------- bucket build (bucket = dst >> 6) ----------------
__global__ __launch_bounds__(256) void k_bhist(const int* __restrict__ dst,
                                               int* __restrict__ bcount, int E, int nb) {
    __shared__ int h[2048];
    for (int i = threadIdx.x; i < nb; i += 256) h[i] = 0;
    __syncthreads();
    int stride = gridDim.x * 256;
    for (int e = blockIdx.x * 256 + threadIdx.x; e < E; e += stride)
        atomicAdd(&h[dst[e] >> 6], 1);
    __syncthreads();
    for (int i = threadIdx.x; i < nb; i += 256)
        if (h[i]) atomicAdd(&bcount[i], h[i]);
}

__global__ void k_bscan(const int* __restrict__ bcount, int* __restrict__ bstart,
                        int* __restrict__ bcursor, int nb, int E) {
    __shared__ int s[2048];
    int t = threadIdx.x;                 // 1024 threads
    s[t]        = (t < nb) ? bcount[t] : 0;
    s[t + 1024] = (t + 1024 < nb) ? bcount[t + 1024] : 0;
    __syncthreads();
    for (int o = 1; o < 2048; o <<= 1) {
        int a = (t >= o) ? s[t - o] : 0;
        int b = (t + 1024 >= o) ? s[t + 1024 - o] : 0;
        __syncthreads();
        s[t] += a; s[t + 1024] += b;
        __syncthreads();
    }
    if (t < nb) {
        int ex = s[t] - bcount[t];
        bstart[t] = ex; bcursor[t * CURPAD] = ex;
    }
    int t2 = t + 1024;
    if (t2 < nb) {
        int ex = s[t2] - bcount[t2];
        bstart[t2] = ex; bcursor[t2 * CURPAD] = ex;
    }
    if (t == 0) bstart[nb] = E;
}

// rec = (dst&63)<<20 | src  (src < 2^20)
__global__ __launch_bounds__(256) void k_bfill(const int* __restrict__ src,
        const int* __restrict__ dst, int* __restrict__ bcursor,
        unsigned int* __restrict__ barr, int E) {
    int e = blockIdx.x * 256 + threadIdx.x;
    if (e < E) {
        int d = dst[e];
        unsigned int rec = ((unsigned int)(d & 63) << 20) | (unsigned int)src[e];
        int pos = atomicAdd(&bcursor[(d >> 6) * CURPAD], 1);
        barr[pos] = rec;
    }
}

// ---------------- per-bucket counting sort -> node-sorted CSR -------------
// Block per bucket. Writes csr[bstart[b] .. bstart[b+1]) (contiguous window)
// and row_start for the bucket's 64 nodes. Handles any bucket size.
__global__ __launch_bounds__(256) void k_bsort(const unsigned int* __restrict__ barr,
        const int* __restrict__ bstart, int* __restrict__ csr,
        int* __restrict__ row_start, int n, int nb, int E) {
    __shared__ int hist[64], offs[64], curs[64];
    int tid = threadIdx.x;
    int b = blockIdx.x, nb0 = b << 6;
    int e0 = bstart[b], e1 = bstart[b + 1];
    if (tid < 64) hist[tid] = 0;
    __syncthreads();
    for (int t = e0 + tid; t < e1; t += 256)
        atomicAdd(&hist[barr[t] >> 20], 1);
    __syncthreads();
    if (tid == 0) {
        int run = 0;
#pragma unroll
        for (int i = 0; i < 64; ++i) { offs[i] = run; run += hist[i]; }
    }
    __syncthreads();
    if (tid < 64) {
        curs[tid] = offs[tid];
        int node = nb0 + tid;
        if (node < n) row_start[node] = e0 + offs[tid];
    }
    if (b == nb - 1 && tid == 0) row_start[n] = E;
    __syncthreads();
    for (int t = e0 + tid; t < e1; t += 256) {
        unsigned int rec = barr[t];
        int pos = atomicAdd(&curs[rec >> 20], 1);
        csr[e0 + pos] = (int)(rec & 0xFFFFF);
    }
}

// ---------------- aggregation (pull, wave per node, coalesced rows) -------
template<bool BF>
__device__ __forceinline__ void agg0_impl(const void* x, const int* rs, const int* csr,
                                          u16* agg, int n) {
    int i = blockIdx.x * 4 + (threadIdx.x >> 6);
    if (i >= n) return;
    int lane = threadIdx.x & 63;
    int h = lane >> 5, cp = lane & 31;
    int b = rs[i], e = rs[i + 1];
    float a0 = 0.f, a1 = 0.f, b0 = 0.f, b1 = 0.f;
    int t = b + h;
    for (; t + 2 < e; t += 4) {
        int j0 = csr[t], j1 = csr[t + 2];
        if (BF) {
            unsigned int w0 = ((const unsigned int*)x)[(long)j0 * 32 + cp];
            unsigned int w1 = ((const unsigned int*)x)[(long)j1 * 32 + cp];
            a0 += lo16(w0); a1 += hi16(w0);
            b0 += lo16(w1); b1 += hi16(w1);
        } else {
            float2 w0 = ((const float2*)x)[(long)j0 * 32 + cp];
            float2 w1 = ((const float2*)x)[(long)j1 * 32 + cp];
            a0 += w0.x; a1 += w0.y;
            b0 += w1.x; b1 += w1.y;
        }
    }
    for (; t < e; t += 2) {
        int j0 = csr[t];
        if (BF) {
            unsigned int w0 = ((const unsigned int*)x)[(long)j0 * 32 + cp];
            a0 += lo16(w0); a1 += hi16(w0);
        } else {
            float2 w0 = ((const float2*)x)[(long)j0 * 32 + cp];
            a0 += w0.x; a1 += w0.y;
        }
    }
    a0 += b0; a1 += b1;
    a0 += __shfl_xor(a0, 32);
    a1 += __shfl_xor(a1, 32);
    if (h == 0) {
        unsigned int o = (unsigned int)f2bf(a0) | ((unsigned int)f2bf(a1) << 16);
        ((unsigned int*)agg)[(long)i * 32 + cp] = o;
    }
}

__global__ __launch_bounds__(256) void k_agg0(const int* __restrict__ flag,
        const void* x, const int* __restrict__ rs, const int* __restrict__ csr,
        u16* __restrict__ agg, int n) {
    if (*flag) agg0_impl<true >(x, rs, csr, agg, n);
    else       agg0_impl<false>(x, rs, csr, agg, n);
}

// agg1: gathers relu(bn0(y0_raw)); scale/shift applied on the fly. bf16 internal.
__global__ __launch_bounds__(256) void k_agg1(const u16* __restrict__ y0,
        const int* __restrict__ rs, const int* __restrict__ csr,
        const float* __restrict__ scale, const float* __restrict__ shift,
        u16* __restrict__ agg, int n) {
    int i = blockIdx.x * 4 + (threadIdx.x >> 6);
    if (i >= n) return;
    int lane = threadIdx.x & 63;
    int c0 = 2 * lane;
    float s0 = scale[c0], s1 = scale[c0 + 1];
    float h0 = shift[c0], h1 = shift[c0 + 1];
    const unsigned int* y32 = (const unsigned int*)y0;
    int b = rs[i], e = rs[i + 1];
    float a0 = 0.f, a1 = 0.f, b0 = 0.f, b1 = 0.f;
    float c0a = 0.f, c1a = 0.f, d0 = 0.f, d1 = 0.f;
    int t = b;
    for (; t + 4 <= e; t += 4) {
        int j0 = csr[t], j1 = csr[t + 1], j2 = csr[t + 2], j3 = csr[t + 3];
        unsigned int w0 = y32[(long)j0 * 64 + lane];
        unsigned int w1 = y32[(long)j1 * 64 + lane];
        unsigned int w2 = y32[(long)j2 * 64 + lane];
        unsigned int w3 = y32[(long)j3 * 64 + lane];
        a0  += fmaxf(lo16(w0) * s0 + h0, 0.f); a1  += fmaxf(hi16(w0) * s1 + h1, 0.f);
        b0  += fmaxf(lo16(w1) * s0 + h0, 0.f); b1  += fmaxf(hi16(w1) * s1 + h1, 0.f);
        c0a += fmaxf(lo16(w2) * s0 + h0, 0.f); c1a += fmaxf(hi16(w2) * s1 + h1, 0.f);
        d0  += fmaxf(lo16(w3) * s0 + h0, 0.f); d1  += fmaxf(hi16(w3) * s1 + h1, 0.f);
    }
    for (; t < e; ++t) {
        unsigned int w0 = y32[(long)csr[t] * 64 + lane];
        a0 += fmaxf(lo16(w0) * s0 + h0, 0.f); a1 += fmaxf(hi16(w0) * s1 + h1, 0.f);
    }
    float s0t = (a0 + b0) + (c0a + d0);
    float s1t = (a1 + b1) + (c1a + d1);
    ((unsigned int*)agg)[(long)i * 64 + lane] =
        (unsigned int)f2bf(s0t) | ((unsigned int)f2bf(s1t) << 16);
}

// ---------------- GEMM0: y0 = [x|agg0] @ [Wr0;Wn0]^T, fused stats ----------
template<bool BF>
__device__ __forceinline__ void gemm0_impl(const void* x, const u16* agg,
                                           const void* Wr, const void* Wn,
                                           u16* y0, float* sum, float* sumsq,
                                           int n, u16* lds) {
    const int ST = 130;
    int tid = threadIdx.x;
    int wave = tid >> 6, lane = tid & 63, lr = lane & 15, q = lane >> 4;
    long chunk0 = (long)blockIdx.x * 64;

    short8 wf[2][4];
#pragma unroll
    for (int i = 0; i < 2; ++i) {
        int c = (2 * wave + i) * 16 + lr;
#pragma unroll
        for (int ks = 0; ks < 4; ++ks) {
            const void* W = (ks < 2) ? Wr : Wn;
            wf[i][ks] = ld8<BF>(W, (long)c * CIN + (ks & 1) * 32 + q * 8);
        }
    }
    stage_tile<BF, 64>(x, chunk0, lds, ST, 0, n, tid);
    stage_tile<true, 64>(agg, chunk0, lds, ST, 64, n, tid);
    __syncthreads();

    float st[2] = {0.f, 0.f}, sq[2] = {0.f, 0.f};
#pragma unroll
    for (int t = 0; t < 4; ++t) {
        short8 a[4];
#pragma unroll
        for (int ks = 0; ks < 4; ++ks)
            a[ks] = *(const short8*)(lds + (t * 16 + lr) * ST + ks * 32 + q * 8);
#pragma unroll
        for (int i = 0; i < 2; ++i) {
            f32x4 acc = {0.f, 0.f, 0.f, 0.f};
#pragma unroll
            for (int ks = 0; ks < 4; ++ks)
                acc = __builtin_amdgcn_mfma_f32_16x16x32_bf16(a[ks], wf[i][ks], acc, 0, 0, 0);
            int c = (2 * wave + i) * 16 + lr;
#pragma unroll
            for (int r = 0; r < 4; ++r) {
                long row = chunk0 + t * 16 + q * 4 + r;
                if (row < n) {
                    y0[row * COUT + c] = f2bf(acc[r]);   // b0 cancels in BN
                    st[i] += acc[r]; sq[i] += acc[r] * acc[r];
                }
            }
        }
    }
#pragma unroll
    for (int i = 0; i < 2; ++i) {
        st[i] += __shfl_xor(st[i], 16); st[i] += __shfl_xor(st[i], 32);
        sq[i] += __shfl_xor(sq[i], 16); sq[i] += __shfl_xor(sq[i], 32);
    }
    if (q == 0) {
#pragma unroll
        for (int i = 0; i < 2; ++i) {
            int c = (2 * wave + i) * 16 + lr;
            atomicAdd(&sum[c], st[i]);
            atomicAdd(&sumsq[c], sq[i]);
        }
    }
}

__global__ __launch_bounds__(256) void k_gemm0(const int* __restrict__ flag,
        const void* x, const u16* __restrict__ agg, const void* Wr, const void* Wn,
        u16* __restrict__ y0, float* __restrict__ sum, float* __restrict__ sumsq, int n) {
    __shared__ u16 lds[64 * 130];
    if (*flag) gemm0_impl<true >(x, agg, Wr, Wn, y0, sum, sumsq, n, lds);
    else       gemm0_impl<false>(x, agg, Wr, Wn, y0, sum, sumsq, n, lds);
}

// ---------------- GEMM1: y1 = [relu(bn0(y0))|agg1] @ [Wr1;Wn1]^T, stats ----
template<bool BF>
__device__ __forceinline__ void gemm1_impl(const u16* y0, const u16* agg,
                                           const void* Wr, const void* Wn,
                                           const float* sc0, const float* sh0,
                                           u16* y1, float* sum, float* sumsq,
                                           int n, u16* lds) {
    const int ST = 258;
    int tid = threadIdx.x;
    int wave = tid >> 6, lane = tid & 63, lr = lane & 15, q = lane >> 4;
    long chunk0 = (long)blockIdx.x * 64;

    short8 wf[2][8];
#pragma unroll
    for (int i = 0; i < 2; ++i) {
        int c = (2 * wave + i) * 16 + lr;
#pragma unroll
        for (int ks = 0; ks < 8; ++ks) {
            const void* W = (ks < 4) ? Wr : Wn;
            wf[i][ks] = ld8<BF>(W, (long)c * COUT + (ks & 3) * 32 + q * 8);
        }
    }
    stage_y0p(y0, chunk0, lds, ST, sc0, sh0, n, tid);
    stage_tile<true, 128>(agg, chunk0, lds, ST, 128, n, tid);
    __syncthreads();

    float st[2] = {0.f, 0.f}, sq[2] = {0.f, 0.f};
#pragma unroll
    for (int t = 0; t < 4; ++t) {
        short8 a[8];
#pragma unroll
        for (int ks = 0; ks < 8; ++ks)
            a[ks] = *(const short8*)(lds + (t * 16 + lr) * ST + ks * 32 + q * 8);
#pragma unroll
        for (int i = 0; i < 2; ++i) {
            f32x4 acc = {0.f, 0.f, 0.f, 0.f};
#pragma unroll
            for (int ks = 0; ks < 8; ++ks)
                acc = __builtin_amdgcn_mfma_f32_16x16x32_bf16(a[ks], wf[i][ks], acc, 0, 0, 0);
            int c = (2 * wave + i) * 16 + lr;
#pragma unroll
            for (int r = 0; r < 4; ++r) {
                long row = chunk0 + t * 16 + q * 4 + r;
                if (row < n) {
                    y1[row * COUT + c] = f2bf(acc[r]);   // b1 cancels in BN
                    st[i] += acc[r]; sq[i] += acc[r] * acc[r];
                }
            }
        }
    }
#pragma unroll
    for (int i = 0; i < 2; ++i) {
        st[i] += __shfl_xor(st[i], 16); st[i] += __shfl_xor(st[i], 32);
        sq[i] += __shfl_xor(sq[i], 16); sq[i] += __shfl_xor(sq[i], 32);
    }
    if (q == 0) {
#pragma unroll
        for (int i = 0; i < 2; ++i) {
            int c = (2 * wave + i) * 16 + lr;
            atomicAdd(&sum[c], st[i]);
            atomicAdd(&sumsq[c], sq[i]);
        }
    }
}

__global__ __launch_bounds__(256) void k_gemm1(const int* __restrict__ flag,
        const u16* __restrict__ y0, const u16* __restrict__ agg,
        const void* Wr, const void* Wn,
        const float* __restrict__ sc0, const float* __restrict__ sh0,
        u16* y1_bf /*=d_out*/, u16* y1_ws,
        float* __restrict__ sum, float* __restrict__ sumsq, int n) {
    __shared__ u16 lds[64 * 258];
    u16* y1 = *flag ? y1_bf : y1_ws;
    if (*flag) gemm1_impl<true >(y0, agg, Wr, Wn, sc0, sh0, y1, sum, sumsq, n, lds);
    else       gemm1_impl<false>(y0, agg, Wr, Wn, sc0, sh0, y1, sum, sumsq, n, lds);
}

// ---------------- BN finalize ----------------
__global__ void k_bnfin(const int* __restrict__ flag,
                        const float* __restrict__ sum, const float* __restrict__ sumsq,
                        const void* g, const void* be,
                        float* __restrict__ scale, float* __restrict__ shift, int n) {
    int c = threadIdx.x;
    bool bf = (*flag != 0);
    float inv = 1.f / (float)n;
    float mu = sum[c] * inv;
    float var = fmaxf(sumsq[c] * inv - mu * mu, 0.f);
    float gv = bf ? bf2f(((const u16*)g)[c]) : ((const float*)g)[c];
    float bv = bf ? bf2f(((const u16*)be)[c]) : ((const float*)be)[c];
    float sc = gv * rsqrtf(var + BN_EPS);
    scale[c] = sc;
    shift[c] = bv - mu * sc;
}

// ---------------- final: out = relu(bn1(y1) + x@Wlin^T + blin) ------------
template<bool BF>
__device__ __forceinline__ void final_impl(const void* x, const u16* y1,
                                           const void* Wlin, const void* blin,
                                           const float* sc, const float* sh,
                                           void* out, int n, u16* lds) {
    const int ST = 194;
    int tid = threadIdx.x;
    int wave = tid >> 6, lane = tid & 63, lr = lane & 15, q = lane >> 4;
    long chunk0 = (long)blockIdx.x * 64;

    short8 wf[2][2];
    float blc[2], scc[2], shc[2];
#pragma unroll
    for (int i = 0; i < 2; ++i) {
        int c = (2 * wave + i) * 16 + lr;
#pragma unroll
        for (int ks = 0; ks < 2; ++ks)
            wf[i][ks] = ld8<BF>(Wlin, (long)c * CIN + ks * 32 + q * 8);
        blc[i] = ldf<BF>(blin, c);
        scc[i] = sc[c]; shc[i] = sh[c];
    }
    stage_tile<BF, 64>(x, chunk0, lds, ST, 0, n, tid);
    stage_tile<true, 128>(y1, chunk0, lds, ST, 64, n, tid);
    __syncthreads();

#pragma unroll
    for (int t = 0; t < 4; ++t) {
        short8 a[2];
#pragma unroll
        for (int ks = 0; ks < 2; ++ks)
            a[ks] = *(const short8*)(lds + (t * 16 + lr) * ST + ks * 32 + q * 8);
#pragma unroll
        for (int i = 0; i < 2; ++i) {
            f32x4 acc = {0.f, 0.f, 0.f, 0.f};
            acc = __builtin_amdgcn_mfma_f32_16x16x32_bf16(a[0], wf[i][0], acc, 0, 0, 0);
            acc = __builtin_amdgcn_mfma_f32_16x16x32_bf16(a[1], wf[i][1], acc, 0, 0, 0);
            int c = (2 * wave + i) * 16 + lr;
#pragma unroll
            for (int r = 0; r < 4; ++r) {
                long row = chunk0 + t * 16 + q * 4 + r;
                if (row < n) {
                    float yv = bf2f(lds[(t * 16 + q * 4 + r) * ST + 64 + c]);
                    float v = acc[r] + blc[i] + yv * scc[i] + shc[i];
                    v = fmaxf(v, 0.f);
                    if (BF) ((u16*)out)[row * COUT + c] = f2bf(v);
                    else    ((float*)out)[row * COUT + c] = v;
                }
            }
        }
    }
}

__global__ __launch_bounds__(256) void k_final(const int* __restrict__ flag,
        const void* x, const void* Wlin, const void* blin,
        const u16* y1_bf /*=d_out*/, const u16* y1_ws,
        const float* __restrict__ sc, const float* __restrict__ sh,
        void* out, int n) {
    __shared__ u16 lds[64 * 194];
    const u16* y1 = *flag ? y1_bf : y1_ws;
    if (*flag) final_impl<true >(x, y1, Wlin, blin, sc, sh, out, n, lds);
    else       final_impl<false>(x, y1, Wlin, blin, sc, sh, out, n, lds);
}

extern "C" void kernel_launch(void* const* d_in, const int* in_sizes, int n_in,
                              void* d_out, int out_size, void* d_ws, size_t ws_size,
                              hipStream_t stream) {
    (void)n_in; (void)out_size; (void)ws_size;
    const void* x    = d_in[0];
    const int*  ei   = (const int*)d_in[1];
    const void* Wr0  = d_in[2];
    const void* Wn0  = d_in[3];
    /* b0 dropped: BN-invariant */
    const void* g0   = d_in[5];
    const void* be0  = d_in[6];
    const void* Wr1  = d_in[7];
    const void* Wn1  = d_in[8];
    /* b1 dropped */
    const void* g1   = d_in[10];
    const void* be1  = d_in[11];
    const void* Wlin = d_in[12];
    const void* blin = d_in[13];

    const int N = in_sizes[0] / CIN;
    const int E = in_sizes[1] / 2;
    const int* src = ei;
    const int* dst = ei + E;
    const int NB = (N + 63) >> 6;   // 64-node buckets; NB <= 2048 for N <= 131072

    // ---- workspace carve (256B aligned); f32-only region LAST ----
    char* base = (char*)d_ws;
    size_t off = 0;
    auto carve = [&](size_t bytes) -> void* {
        void* p = base + off;
        off = (off + bytes + 255) & ~(size_t)255;
        return p;
    };
    int*   flag      = (int*)carve(256);
    int*   bcount    = (int*)carve(2048 * sizeof(int));
    int*   bstart    = (int*)carve(2049 * sizeof(int));
    int*   bcursor   = (int*)carve(2048 * CURPAD * sizeof(int));
    float* stats     = (float*)carve(512 * sizeof(float));  // sum0,sq0,sum1,sq1
    float* scsh      = (float*)carve(512 * sizeof(float));  // scale0,shift0,scale1,shift1
    int*   row_start = (int*)carve((size_t)(N + 1) * sizeof(int));
    unsigned int* barr = (unsigned int*)carve((size_t)E * sizeof(int));
    int*   csr       = (int*)carve((size_t)E * sizeof(int));
    u16*   aggu      = (u16*)carve((size_t)N * COUT * sizeof(u16)); // agg0 aliases agg1
    u16*   y0        = (u16*)carve((size_t)N * COUT * sizeof(u16));
    u16*   y1_ws     = (u16*)carve((size_t)N * COUT * sizeof(u16)); // f32 mode only

    hipMemsetAsync(bcount, 0, 2048 * sizeof(int), stream);
    hipMemsetAsync(stats, 0, 512 * sizeof(float), stream);

    const int eb  = (E + 255) / 256;
    const int nwb = (N + 3) / 4;       // wave-per-node blocks
    const int nch = (N + 63) / 64;     // 64-row chunks for dense kernels

    k_detect<<<1, 64, 0, stream>>>((const unsigned int*)x, flag);

    k_bhist<<<256, 256, 0, stream>>>(dst, bcount, E, NB);
    k_bscan<<<1, 1024, 0, stream>>>(bcount, bstart, bcursor, NB, E);
    k_bfill<<<eb, 256, 0, stream>>>(src, dst, bcursor, barr, E);
    k_bsort<<<NB, 256, 0, stream>>>(barr, bstart, csr, row_start, N, NB, E);

    k_agg0 <<<nwb, 256, 0, stream>>>(flag, x, row_start, csr, aggu, N);
    k_gemm0<<<nch, 256, 0, stream>>>(flag, x, aggu, Wr0, Wn0, y0,
                                     stats, stats + 128, N);
    k_bnfin<<<1, 128, 0, stream>>>(flag, stats, stats + 128, g0, be0,
                                   scsh, scsh + 128, N);

    k_agg1 <<<nwb, 256, 0, stream>>>(y0, row_start, csr, scsh, scsh + 128, aggu, N);
    k_gemm1<<<nch, 256, 0, stream>>>(flag, y0, aggu, Wr1, Wn1, scsh, scsh + 128,
                                     (u16*)d_out, y1_ws, stats + 256, stats + 384, N);
    k_bnfin<<<1, 128, 0, stream>>>(flag, stats + 256, stats + 384, g1, be1,
                                   scsh + 256, scsh + 384, N);

    k_final<<<nch, 256, 0, stream>>>(flag, x, Wlin, blin,
                                     (const u16*)d_out, y1_ws,
                                     scsh + 256, scsh + 384, d_out, N);
}

// Round 7
// 501.293 us; speedup vs baseline: 4.2289x; 1.0158x over previous
//
#include <hip/hip_runtime.h>
#include <stdint.h>

// ResBlock: GraphConv(64->128) -> BN -> ReLU -> GraphConv(128->128) -> BN
//           + (x @ Wlin^T + blin) residual -> ReLU.
// Runtime dtype probe (bf16 vs f32).
// R6->R7: k_bfill XCD-partitioned (bucket&7 == blockIdx&7): all writers of a
// barr cache line live on ONE XCD -> kills the 12x inter-XCD partial-line
// write amplification (WRITE_SIZE 80MB for a 6.4MB array). Rest unchanged.

#define CIN 64
#define COUT 128
#define BN_EPS 1e-5f
#define CURPAD 16

typedef unsigned short u16;
typedef short short8 __attribute__((ext_vector_type(8)));
typedef float f32x4 __attribute__((ext_vector_type(4)));

__device__ __forceinline__ float bf2f(u16 u) {
    union { unsigned int i; float f; } v; v.i = ((unsigned int)u) << 16; return v.f;
}
__device__ __forceinline__ u16 f2bf(float f) {
    union { float f; unsigned int i; } v; v.f = f;
    unsigned int r = v.i + 0x7fffu + ((v.i >> 16) & 1u);  // RNE; finite inputs
    return (u16)(r >> 16);
}
__device__ __forceinline__ float lo16(unsigned int w) { return bf2f((u16)(w & 0xffffu)); }
__device__ __forceinline__ float hi16(unsigned int w) { return bf2f((u16)(w >> 16)); }

template<bool BF> __device__ __forceinline__ float ldf(const void* p, long i) {
    if (BF) return bf2f(((const u16*)p)[i]);
    return ((const float*)p)[i];
}
template<bool BF> __device__ __forceinline__ short8 ld8(const void* p, long i) {
    if (BF) return *(const short8*)((const u16*)p + i);
    const float* f = (const float*)p + i;
    short8 r;
#pragma unroll
    for (int j = 0; j < 8; ++j) r[j] = (short)f2bf(f[j]);
    return r;
}

// ---- coalesced 64-row chunk staging into padded LDS (bf16 in LDS) --------
template<bool BF, int RL>
__device__ __forceinline__ void stage_tile(const void* g, long first_row,
                                           u16* lds, int stride, int col_off,
                                           int n, int tid) {
    if (BF) {
        const int SPR = RL / 8;
        const int NPT = 64 * SPR / 256;
#pragma unroll
        for (int i = 0; i < NPT; ++i) {
            int s = tid + i * 256;
            int row = s / SPR, within = s % SPR;
            long rg = first_row + row; if (rg > n - 1) rg = n - 1;
            short8 v = *(const short8*)((const u16*)g + rg * RL + within * 8);
            *(short8*)(lds + row * stride + col_off + within * 8) = v;
        }
    } else {
        const int SPR = RL / 4;
        const int NPT = 64 * SPR / 256;
#pragma unroll
        for (int i = 0; i < NPT; ++i) {
            int s = tid + i * 256;
            int row = s / SPR, within = s % SPR;
            long rg = first_row + row; if (rg > n - 1) rg = n - 1;
            float4 v = *(const float4*)((const float*)g + rg * RL + within * 4);
            u16* d = lds + row * stride + col_off + within * 4;
            d[0] = f2bf(v.x); d[1] = f2bf(v.y); d[2] = f2bf(v.z); d[3] = f2bf(v.w);
        }
    }
}

// stage y0 (bf16) with fused BN0-apply + ReLU
__device__ __forceinline__ void stage_y0p(const u16* y0, long first_row,
                                          u16* lds, int stride,
                                          const float* __restrict__ sc,
                                          const float* __restrict__ sh,
                                          int n, int tid) {
#pragma unroll
    for (int i = 0; i < 4; ++i) {
        int s = tid + i * 256;
        int row = s >> 4, within = s & 15;
        long rg = first_row + row; if (rg > n - 1) rg = n - 1;
        short8 v = *(const short8*)(y0 + rg * COUT + within * 8);
        int c = within * 8;
        short8 o;
#pragma unroll
        for (int j = 0; j < 8; ++j)
            o[j] = (short)f2bf(fmaxf(bf2f((u16)v[j]) * sc[c + j] + sh[c + j], 0.f));
        *(short8*)(lds + row * stride + within * 8) = o;
    }
}

// ---------------- dtype detection ----------------
__global__ void k_detect(const unsigned int* __restrict__ x, int* __restrict__ flag) {
    int lane = threadIdx.x;  // 64
    int cnt = 0;
#pragma unroll
    for (int i = 0; i < 8; ++i) {
        unsigned int w = x[lane * 8 + i];
        unsigned int e0 = (w >> 7) & 0xFFu, e1 = (w >> 23) & 0xFFu;
        cnt += (e0 >= 0x60u && e0 <= 0x8Eu);
        cnt += (e1 >= 0x60u && e1 <= 0x8Eu);
    }
    for (int o = 32; o; o >>= 1) cnt += __shfl_down(cnt, o);
    if (lane == 0) *flag = (cnt > 850) ? 1 : 0;   // 1 => bf16
}

// ---------------- bucket build (bucket = dst >> 6) ----------------
__global__ __launch_bounds__(256) void k_bhist(const int* __restrict__ dst,
                                               int* __restrict__ bcount, int E, int nb) {
    __shared__ int h[2048];
    for (int i = threadIdx.x; i < nb; i += 256) h[i] = 0;
    __syncthreads();
    int stride = gridDim.x * 256;
    for (int e = blockIdx.x * 256 + threadIdx.x; e < E; e += stride)
        atomicAdd(&h[dst[e] >> 6], 1);
    __syncthreads();
    for (int i = threadIdx.x; i < nb; i += 256)
        if (h[i]) atomicAdd(&bcount[i], h[i]);
}

__global__ void k_bscan(const int* __restrict__ bcount, int* __restrict__ bstart,
                        int* __restrict__ bcursor, int nb, int E) {
    __shared__ int s[2048];
    int t = threadIdx.x;                 // 1024 threads
    s[t]        = (t < nb) ? bcount[t] : 0;
    s[t + 1024] = (t + 1024 < nb) ? bcount[t + 1024] : 0;
    __syncthreads();
    for (int o = 1; o < 2048; o <<= 1) {
        int a = (t >= o) ? s[t - o] : 0;
        int b = (t + 1024 >= o) ? s[t + 1024 - o] : 0;
        __syncthreads();
        s[t] += a; s[t + 1024] += b;
        __syncthreads();
    }
    if (t < nb) {
        int ex = s[t] - bcount[t];
        bstart[t] = ex; bcursor[t * CURPAD] = ex;
    }
    int t2 = t + 1024;
    if (t2 < nb) {
        int ex = s[t2] - bcount[t2];
        bstart[t2] = ex; bcursor[t2 * CURPAD] = ex;
    }
    if (t == 0) bstart[nb] = E;
}

// rec = (dst&63)<<20 | src  (src < 2^20)
// XCD-partitioned: blocks with (blockIdx&7)==p handle only buckets with
// (bucket&7)==p, so each barr cache line is written by exactly one XCD.
// Blocks (blockIdx>>3) slice the edge list within a partition.
__global__ __launch_bounds__(256) void k_bfill(const int* __restrict__ src,
        const int* __restrict__ dst, int* __restrict__ bcursor,
        unsigned int* __restrict__ barr, int E) {
    int part   = blockIdx.x & 7;
    int slice  = blockIdx.x >> 3;
    int nsl    = gridDim.x >> 3;
    int stride = nsl * 256;
    for (int e = slice * 256 + threadIdx.x; e < E; e += stride) {
        int d = dst[e];
        int b = d >> 6;
        if ((b & 7) == part) {
            unsigned int rec = ((unsigned int)(d & 63) << 20) | (unsigned int)src[e];
            int pos = atomicAdd(&bcursor[b * CURPAD], 1);
            barr[pos] = rec;
        }
    }
}

// ---------------- per-bucket counting sort -> node-sorted CSR -------------
// Block per bucket (block b -> XCD b&7 = the L2 that owns bucket b's barr).
__global__ __launch_bounds__(256) void k_bsort(const unsigned int* __restrict__ barr,
        const int* __restrict__ bstart, int* __restrict__ csr,
        int* __restrict__ row_start, int n, int nb, int E) {
    __shared__ int hist[64], offs[64], curs[64];
    int tid = threadIdx.x;
    int b = blockIdx.x, nb0 = b << 6;
    int e0 = bstart[b], e1 = bstart[b + 1];
    if (tid < 64) hist[tid] = 0;
    __syncthreads();
    for (int t = e0 + tid; t < e1; t += 256)
        atomicAdd(&hist[barr[t] >> 20], 1);
    __syncthreads();
    if (tid == 0) {
        int run = 0;
#pragma unroll
        for (int i = 0; i < 64; ++i) { offs[i] = run; run += hist[i]; }
    }
    __syncthreads();
    if (tid < 64) {
        curs[tid] = offs[tid];
        int node = nb0 + tid;
        if (node < n) row_start[node] = e0 + offs[tid];
    }
    if (b == nb - 1 && tid == 0) row_start[n] = E;
    __syncthreads();
    for (int t = e0 + tid; t < e1; t += 256) {
        unsigned int rec = barr[t];
        int pos = atomicAdd(&curs[rec >> 20], 1);
        csr[e0 + pos] = (int)(rec & 0xFFFFF);
    }
}

// ---------------- aggregation (pull, wave per node, coalesced rows) -------
template<bool BF>
__device__ __forceinline__ void agg0_impl(const void* x, const int* rs, const int* csr,
                                          u16* agg, int n) {
    int i = blockIdx.x * 4 + (threadIdx.x >> 6);
    if (i >= n) return;
    int lane = threadIdx.x & 63;
    int h = lane >> 5, cp = lane & 31;
    int b = rs[i], e = rs[i + 1];
    float a0 = 0.f, a1 = 0.f, b0 = 0.f, b1 = 0.f;
    int t = b + h;
    for (; t + 2 < e; t += 4) {
        int j0 = csr[t], j1 = csr[t + 2];
        if (BF) {
            unsigned int w0 = ((const unsigned int*)x)[(long)j0 * 32 + cp];
            unsigned int w1 = ((const unsigned int*)x)[(long)j1 * 32 + cp];
            a0 += lo16(w0); a1 += hi16(w0);
            b0 += lo16(w1); b1 += hi16(w1);
        } else {
            float2 w0 = ((const float2*)x)[(long)j0 * 32 + cp];
            float2 w1 = ((const float2*)x)[(long)j1 * 32 + cp];
            a0 += w0.x; a1 += w0.y;
            b0 += w1.x; b1 += w1.y;
        }
    }
    for (; t < e; t += 2) {
        int j0 = csr[t];
        if (BF) {
            unsigned int w0 = ((const unsigned int*)x)[(long)j0 * 32 + cp];
            a0 += lo16(w0); a1 += hi16(w0);
        } else {
            float2 w0 = ((const float2*)x)[(long)j0 * 32 + cp];
            a0 += w0.x; a1 += w0.y;
        }
    }
    a0 += b0; a1 += b1;
    a0 += __shfl_xor(a0, 32);
    a1 += __shfl_xor(a1, 32);
    if (h == 0) {
        unsigned int o = (unsigned int)f2bf(a0) | ((unsigned int)f2bf(a1) << 16);
        ((unsigned int*)agg)[(long)i * 32 + cp] = o;
    }
}

__global__ __launch_bounds__(256) void k_agg0(const int* __restrict__ flag,
        const void* x, const int* __restrict__ rs, const int* __restrict__ csr,
        u16* __restrict__ agg, int n) {
    if (*flag) agg0_impl<true >(x, rs, csr, agg, n);
    else       agg0_impl<false>(x, rs, csr, agg, n);
}

// agg1: gathers relu(bn0(y0_raw)); scale/shift applied on the fly. bf16 internal.
__global__ __launch_bounds__(256) void k_agg1(const u16* __restrict__ y0,
        const int* __restrict__ rs, const int* __restrict__ csr,
        const float* __restrict__ scale, const float* __restrict__ shift,
        u16* __restrict__ agg, int n) {
    int i = blockIdx.x * 4 + (threadIdx.x >> 6);
    if (i >= n) return;
    int lane = threadIdx.x & 63;
    int c0 = 2 * lane;
    float s0 = scale[c0], s1 = scale[c0 + 1];
    float h0 = shift[c0], h1 = shift[c0 + 1];
    const unsigned int* y32 = (const unsigned int*)y0;
    int b = rs[i], e = rs[i + 1];
    float a0 = 0.f, a1 = 0.f, b0 = 0.f, b1 = 0.f;
    float c0a = 0.f, c1a = 0.f, d0 = 0.f, d1 = 0.f;
    int t = b;
    for (; t + 4 <= e; t += 4) {
        int j0 = csr[t], j1 = csr[t + 1], j2 = csr[t + 2], j3 = csr[t + 3];
        unsigned int w0 = y32[(long)j0 * 64 + lane];
        unsigned int w1 = y32[(long)j1 * 64 + lane];
        unsigned int w2 = y32[(long)j2 * 64 + lane];
        unsigned int w3 = y32[(long)j3 * 64 + lane];
        a0  += fmaxf(lo16(w0) * s0 + h0, 0.f); a1  += fmaxf(hi16(w0) * s1 + h1, 0.f);
        b0  += fmaxf(lo16(w1) * s0 + h0, 0.f); b1  += fmaxf(hi16(w1) * s1 + h1, 0.f);
        c0a += fmaxf(lo16(w2) * s0 + h0, 0.f); c1a += fmaxf(hi16(w2) * s1 + h1, 0.f);
        d0  += fmaxf(lo16(w3) * s0 + h0, 0.f); d1  += fmaxf(hi16(w3) * s1 + h1, 0.f);
    }
    for (; t < e; ++t) {
        unsigned int w0 = y32[(long)csr[t] * 64 + lane];
        a0 += fmaxf(lo16(w0) * s0 + h0, 0.f); a1 += fmaxf(hi16(w0) * s1 + h1, 0.f);
    }
    float s0t = (a0 + b0) + (c0a + d0);
    float s1t = (a1 + b1) + (c1a + d1);
    ((unsigned int*)agg)[(long)i * 64 + lane] =
        (unsigned int)f2bf(s0t) | ((unsigned int)f2bf(s1t) << 16);
}

// ---------------- GEMM0: y0 = [x|agg0] @ [Wr0;Wn0]^T, fused stats ----------
template<bool BF>
__device__ __forceinline__ void gemm0_impl(const void* x, const u16* agg,
                                           const void* Wr, const void* Wn,
                                           u16* y0, float* sum, float* sumsq,
                                           int n, u16* lds) {
    const int ST = 130;
    int tid = threadIdx.x;
    int wave = tid >> 6, lane = tid & 63, lr = lane & 15, q = lane >> 4;
    long chunk0 = (long)blockIdx.x * 64;

    short8 wf[2][4];
#pragma unroll
    for (int i = 0; i < 2; ++i) {
        int c = (2 * wave + i) * 16 + lr;
#pragma unroll
        for (int ks = 0; ks < 4; ++ks) {
            const void* W = (ks < 2) ? Wr : Wn;
            wf[i][ks] = ld8<BF>(W, (long)c * CIN + (ks & 1) * 32 + q * 8);
        }
    }
    stage_tile<BF, 64>(x, chunk0, lds, ST, 0, n, tid);
    stage_tile<true, 64>(agg, chunk0, lds, ST, 64, n, tid);
    __syncthreads();

    float st[2] = {0.f, 0.f}, sq[2] = {0.f, 0.f};
#pragma unroll
    for (int t = 0; t < 4; ++t) {
        short8 a[4];
#pragma unroll
        for (int ks = 0; ks < 4; ++ks)
            a[ks] = *(const short8*)(lds + (t * 16 + lr) * ST + ks * 32 + q * 8);
#pragma unroll
        for (int i = 0; i < 2; ++i) {
            f32x4 acc = {0.f, 0.f, 0.f, 0.f};
#pragma unroll
            for (int ks = 0; ks < 4; ++ks)
                acc = __builtin_amdgcn_mfma_f32_16x16x32_bf16(a[ks], wf[i][ks], acc, 0, 0, 0);
            int c = (2 * wave + i) * 16 + lr;
#pragma unroll
            for (int r = 0; r < 4; ++r) {
                long row = chunk0 + t * 16 + q * 4 + r;
                if (row < n) {
                    y0[row * COUT + c] = f2bf(acc[r]);   // b0 cancels in BN
                    st[i] += acc[r]; sq[i] += acc[r] * acc[r];
                }
            }
        }
    }
#pragma unroll
    for (int i = 0; i < 2; ++i) {
        st[i] += __shfl_xor(st[i], 16); st[i] += __shfl_xor(st[i], 32);
        sq[i] += __shfl_xor(sq[i], 16); sq[i] += __shfl_xor(sq[i], 32);
    }
    if (q == 0) {
#pragma unroll
        for (int i = 0; i < 2; ++i) {
            int c = (2 * wave + i) * 16 + lr;
            atomicAdd(&sum[c], st[i]);
            atomicAdd(&sumsq[c], sq[i]);
        }
    }
}

__global__ __launch_bounds__(256) void k_gemm0(const int* __restrict__ flag,
        const void* x, const u16* __restrict__ agg, const void* Wr, const void* Wn,
        u16* __restrict__ y0, float* __restrict__ sum, float* __restrict__ sumsq, int n) {
    __shared__ u16 lds[64 * 130];
    if (*flag) gemm0_impl<true >(x, agg, Wr, Wn, y0, sum, sumsq, n, lds);
    else       gemm0_impl<false>(x, agg, Wr, Wn, y0, sum, sumsq, n, lds);
}

// ---------------- GEMM1: y1 = [relu(bn0(y0))|agg1] @ [Wr1;Wn1]^T, stats ----
template<bool BF>
__device__ __forceinline__ void gemm1_impl(const u16* y0, const u16* agg,
                                           const void* Wr, const void* Wn,
                                           const float* sc0, const float* sh0,
                                           u16* y1, float* sum, float* sumsq,
                                           int n, u16* lds) {
    const int ST = 258;
    int tid = threadIdx.x;
    int wave = tid >> 6, lane = tid & 63, lr = lane & 15, q = lane >> 4;
    long chunk0 = (long)blockIdx.x * 64;

    short8 wf[2][8];
#pragma unroll
    for (int i = 0; i < 2; ++i) {
        int c = (2 * wave + i) * 16 + lr;
#pragma unroll
        for (int ks = 0; ks < 8; ++ks) {
            const void* W = (ks < 4) ? Wr : Wn;
            wf[i][ks] = ld8<BF>(W, (long)c * COUT + (ks & 3) * 32 + q * 8);
        }
    }
    stage_y0p(y0, chunk0, lds, ST, sc0, sh0, n, tid);
    stage_tile<true, 128>(agg, chunk0, lds, ST, 128, n, tid);
    __syncthreads();

    float st[2] = {0.f, 0.f}, sq[2] = {0.f, 0.f};
#pragma unroll
    for (int t = 0; t < 4; ++t) {
        short8 a[8];
#pragma unroll
        for (int ks = 0; ks < 8; ++ks)
            a[ks] = *(const short8*)(lds + (t * 16 + lr) * ST + ks * 32 + q * 8);
#pragma unroll
        for (int i = 0; i < 2; ++i) {
            f32x4 acc = {0.f, 0.f, 0.f, 0.f};
#pragma unroll
            for (int ks = 0; ks < 8; ++ks)
                acc = __builtin_amdgcn_mfma_f32_16x16x32_bf16(a[ks], wf[i][ks], acc, 0, 0, 0);
            int c = (2 * wave + i) * 16 + lr;
#pragma unroll
            for (int r = 0; r < 4; ++r) {
                long row = chunk0 + t * 16 + q * 4 + r;
                if (row < n) {
                    y1[row * COUT + c] = f2bf(acc[r]);   // b1 cancels in BN
                    st[i] += acc[r]; sq[i] += acc[r] * acc[r];
                }
            }
        }
    }
#pragma unroll
    for (int i = 0; i < 2; ++i) {
        st[i] += __shfl_xor(st[i], 16); st[i] += __shfl_xor(st[i], 32);
        sq[i] += __shfl_xor(sq[i], 16); sq[i] += __shfl_xor(sq[i], 32);
    }
    if (q == 0) {
#pragma unroll
        for (int i = 0; i < 2; ++i) {
            int c = (2 * wave + i) * 16 + lr;
            atomicAdd(&sum[c], st[i]);
            atomicAdd(&sumsq[c], sq[i]);
        }
    }
}

__global__ __launch_bounds__(256) void k_gemm1(const int* __restrict__ flag,
        const u16* __restrict__ y0, const u16* __restrict__ agg,
        const void* Wr, const void* Wn,
        const float* __restrict__ sc0, const float* __restrict__ sh0,
        u16* y1_bf /*=d_out*/, u16* y1_ws,
        float* __restrict__ sum, float* __restrict__ sumsq, int n) {
    __shared__ u16 lds[64 * 258];
    u16* y1 = *flag ? y1_bf : y1_ws;
    if (*flag) gemm1_impl<true >(y0, agg, Wr, Wn, sc0, sh0, y1, sum, sumsq, n, lds);
    else       gemm1_impl<false>(y0, agg, Wr, Wn, sc0, sh0, y1, sum, sumsq, n, lds);
}

// ---------------- BN finalize ----------------
__global__ void k_bnfin(const int* __restrict__ flag,
                        const float* __restrict__ sum, const float* __restrict__ sumsq,
                        const void* g, const void* be,
                        float* __restrict__ scale, float* __restrict__ shift, int n) {
    int c = threadIdx.x;
    bool bf = (*flag != 0);
    float inv = 1.f / (float)n;
    float mu = sum[c] * inv;
    float var = fmaxf(sumsq[c] * inv - mu * mu, 0.f);
    float gv = bf ? bf2f(((const u16*)g)[c]) : ((const float*)g)[c];
    float bv = bf ? bf2f(((const u16*)be)[c]) : ((const float*)be)[c];
    float sc = gv * rsqrtf(var + BN_EPS);
    scale[c] = sc;
    shift[c] = bv - mu * sc;
}

// ---------------- final: out = relu(bn1(y1) + x@Wlin^T + blin) ------------
template<bool BF>
__device__ __forceinline__ void final_impl(const void* x, const u16* y1,
                                           const void* Wlin, const void* blin,
                                           const float* sc, const float* sh,
                                           void* out, int n, u16* lds) {
    const int ST = 194;
    int tid = threadIdx.x;
    int wave = tid >> 6, lane = tid & 63, lr = lane & 15, q = lane >> 4;
    long chunk0 = (long)blockIdx.x * 64;

    short8 wf[2][2];
    float blc[2], scc[2], shc[2];
#pragma unroll
    for (int i = 0; i < 2; ++i) {
        int c = (2 * wave + i) * 16 + lr;
#pragma unroll
        for (int ks = 0; ks < 2; ++ks)
            wf[i][ks] = ld8<BF>(Wlin, (long)c * CIN + ks * 32 + q * 8);
        blc[i] = ldf<BF>(blin, c);
        scc[i] = sc[c]; shc[i] = sh[c];
    }
    stage_tile<BF, 64>(x, chunk0, lds, ST, 0, n, tid);
    stage_tile<true, 128>(y1, chunk0, lds, ST, 64, n, tid);
    __syncthreads();

#pragma unroll
    for (int t = 0; t < 4; ++t) {
        short8 a[2];
#pragma unroll
        for (int ks = 0; ks < 2; ++ks)
            a[ks] = *(const short8*)(lds + (t * 16 + lr) * ST + ks * 32 + q * 8);
#pragma unroll
        for (int i = 0; i < 2; ++i) {
            f32x4 acc = {0.f, 0.f, 0.f, 0.f};
            acc = __builtin_amdgcn_mfma_f32_16x16x32_bf16(a[0], wf[i][0], acc, 0, 0, 0);
            acc = __builtin_amdgcn_mfma_f32_16x16x32_bf16(a[1], wf[i][1], acc, 0, 0, 0);
            int c = (2 * wave + i) * 16 + lr;
#pragma unroll
            for (int r = 0; r < 4; ++r) {
                long row = chunk0 + t * 16 + q * 4 + r;
                if (row < n) {
                    float yv = bf2f(lds[(t * 16 + q * 4 + r) * ST + 64 + c]);
                    float v = acc[r] + blc[i] + yv * scc[i] + shc[i];
                    v = fmaxf(v, 0.f);
                    if (BF) ((u16*)out)[row * COUT + c] = f2bf(v);
                    else    ((float*)out)[row * COUT + c] = v;
                }
            }
        }
    }
}

__global__ __launch_bounds__(256) void k_final(const int* __restrict__ flag,
        const void* x, const void* Wlin, const void* blin,
        const u16* y1_bf /*=d_out*/, const u16* y1_ws,
        const float* __restrict__ sc, const float* __restrict__ sh,
        void* out, int n) {
    __shared__ u16 lds[64 * 194];
    const u16* y1 = *flag ? y1_bf : y1_ws;
    if (*flag) final_impl<true >(x, y1, Wlin, blin, sc, sh, out, n, lds);
    else       final_impl<false>(x, y1, Wlin, blin, sc, sh, out, n, lds);
}

extern "C" void kernel_launch(void* const* d_in, const int* in_sizes, int n_in,
                              void* d_out, int out_size, void* d_ws, size_t ws_size,
                              hipStream_t stream) {
    (void)n_in; (void)out_size; (void)ws_size;
    const void* x    = d_in[0];
    const int*  ei   = (const int*)d_in[1];
    const void* Wr0  = d_in[2];
    const void* Wn0  = d_in[3];
    /* b0 dropped: BN-invariant */
    const void* g0   = d_in[5];
    const void* be0  = d_in[6];
    const void* Wr1  = d_in[7];
    const void* Wn1  = d_in[8];
    /* b1 dropped */
    const void* g1   = d_in[10];
    const void* be1  = d_in[11];
    const void* Wlin = d_in[12];
    const void* blin = d_in[13];

    const int N = in_sizes[0] / CIN;
    const int E = in_sizes[1] / 2;
    const int* src = ei;
    const int* dst = ei + E;
    const int NB = (N + 63) >> 6;   // 64-node buckets; NB <= 2048 for N <= 131072

    // ---- workspace carve (256B aligned); f32-only region LAST ----
    char* base = (char*)d_ws;
    size_t off = 0;
    auto carve = [&](size_t bytes) -> void* {
        void* p = base + off;
        off = (off + bytes + 255) & ~(size_t)255;
        return p;
    };
    int*   flag      = (int*)carve(256);
    int*   bcount    = (int*)carve(2048 * sizeof(int));
    int*   bstart    = (int*)carve(2049 * sizeof(int));
    int*   bcursor   = (int*)carve(2048 * CURPAD * sizeof(int));
    float* stats     = (float*)carve(512 * sizeof(float));  // sum0,sq0,sum1,sq1
    float* scsh      = (float*)carve(512 * sizeof(float));  // scale0,shift0,scale1,shift1
    int*   row_start = (int*)carve((size_t)(N + 1) * sizeof(int));
    unsigned int* barr = (unsigned int*)carve((size_t)E * sizeof(int));
    int*   csr       = (int*)carve((size_t)E * sizeof(int));
    u16*   aggu      = (u16*)carve((size_t)N * COUT * sizeof(u16)); // agg0 aliases agg1
    u16*   y0        = (u16*)carve((size_t)N * COUT * sizeof(u16));
    u16*   y1_ws     = (u16*)carve((size_t)N * COUT * sizeof(u16)); // f32 mode only

    hipMemsetAsync(bcount, 0, 2048 * sizeof(int), stream);
    hipMemsetAsync(stats, 0, 512 * sizeof(float), stream);

    const int nwb = (N + 3) / 4;       // wave-per-node blocks
    const int nch = (N + 63) / 64;     // 64-row chunks for dense kernels

    k_detect<<<1, 64, 0, stream>>>((const unsigned int*)x, flag);

    k_bhist<<<256, 256, 0, stream>>>(dst, bcount, E, NB);
    k_bscan<<<1, 1024, 0, stream>>>(bcount, bstart, bcursor, NB, E);
    k_bfill<<<512, 256, 0, stream>>>(src, dst, bcursor, barr, E);  // 8 partitions x 64 slices
    k_bsort<<<NB, 256, 0, stream>>>(barr, bstart, csr, row_start, N, NB, E);

    k_agg0 <<<nwb, 256, 0, stream>>>(flag, x, row_start, csr, aggu, N);
    k_gemm0<<<nch, 256, 0, stream>>>(flag, x, aggu, Wr0, Wn0, y0,
                                     stats, stats + 128, N);
    k_bnfin<<<1, 128, 0, stream>>>(flag, stats, stats + 128, g0, be0,
                                   scsh, scsh + 128, N);

    k_agg1 <<<nwb, 256, 0, stream>>>(y0, row_start, csr, scsh, scsh + 128, aggu, N);
    k_gemm1<<<nch, 256, 0, stream>>>(flag, y0, aggu, Wr1, Wn1, scsh, scsh + 128,
                                     (u16*)d_out, y1_ws, stats + 256, stats + 384, N);
    k_bnfin<<<1, 128, 0, stream>>>(flag, stats + 256, stats + 384, g1, be1,
                                   scsh + 256, scsh + 384, N);

    k_final<<<nch, 256, 0, stream>>>(flag, x, Wlin, blin,
                                     (const u16*)d_out, y1_ws,
                                     scsh + 256, scsh + 384, d_out, N);
}

// Round 8
// 463.928 us; speedup vs baseline: 4.5695x; 1.0805x over previous
//
#include <hip/hip_runtime.h>
#include <stdint.h>

// ResBlock: GraphConv(64->128) -> BN -> ReLU -> GraphConv(128->128) -> BN
//           + (x @ Wlin^T + blin) residual -> ReLU.
// Runtime dtype probe (bf16 vs f32).
// R7->R8: binning rebuilt with NO XCD assumptions (blockIdx&7 trick failed -
// workgroup->XCD mapping is undefined). k_pfill reserves per-(block,partition)
// contiguous runs (tile-local count -> one cursor atomic -> register scatter):
// every barr line written by ~one block. k_psort: block-per-1024-node
// partition does LDS counting sort -> node-sorted csr + row_start directly.
// Aggregation (pull, reg acc) and MFMA GEMMs unchanged.

#define CIN 64
#define COUT 128
#define BN_EPS 1e-5f
#define CURPAD 16
#define PSH 10                 // partition = dst >> PSH  (1024 nodes)
#define PNODES (1 << PSH)
#define MAXP 128               // supports N <= 131072

typedef unsigned short u16;
typedef short short8 __attribute__((ext_vector_type(8)));
typedef float f32x4 __attribute__((ext_vector_type(4)));

__device__ __forceinline__ float bf2f(u16 u) {
    union { unsigned int i; float f; } v; v.i = ((unsigned int)u) << 16; return v.f;
}
__device__ __forceinline__ u16 f2bf(float f) {
    union { float f; unsigned int i; } v; v.f = f;
    unsigned int r = v.i + 0x7fffu + ((v.i >> 16) & 1u);  // RNE; finite inputs
    return (u16)(r >> 16);
}
__device__ __forceinline__ float lo16(unsigned int w) { return bf2f((u16)(w & 0xffffu)); }
__device__ __forceinline__ float hi16(unsigned int w) { return bf2f((u16)(w >> 16)); }

template<bool BF> __device__ __forceinline__ float ldf(const void* p, long i) {
    if (BF) return bf2f(((const u16*)p)[i]);
    return ((const float*)p)[i];
}
template<bool BF> __device__ __forceinline__ short8 ld8(const void* p, long i) {
    if (BF) return *(const short8*)((const u16*)p + i);
    const float* f = (const float*)p + i;
    short8 r;
#pragma unroll
    for (int j = 0; j < 8; ++j) r[j] = (short)f2bf(f[j]);
    return r;
}

// ---- coalesced 64-row chunk staging into padded LDS (bf16 in LDS) --------
template<bool BF, int RL>
__device__ __forceinline__ void stage_tile(const void* g, long first_row,
                                           u16* lds, int stride, int col_off,
                                           int n, int tid) {
    if (BF) {
        const int SPR = RL / 8;
        const int NPT = 64 * SPR / 256;
#pragma unroll
        for (int i = 0; i < NPT; ++i) {
            int s = tid + i * 256;
            int row = s / SPR, within = s % SPR;
            long rg = first_row + row; if (rg > n - 1) rg = n - 1;
            short8 v = *(const short8*)((const u16*)g + rg * RL + within * 8);
            *(short8*)(lds + row * stride + col_off + within * 8) = v;
        }
    } else {
        const int SPR = RL / 4;
        const int NPT = 64 * SPR / 256;
#pragma unroll
        for (int i = 0; i < NPT; ++i) {
            int s = tid + i * 256;
            int row = s / SPR, within = s % SPR;
            long rg = first_row + row; if (rg > n - 1) rg = n - 1;
            float4 v = *(const float4*)((const float*)g + rg * RL + within * 4);
            u16* d = lds + row * stride + col_off + within * 4;
            d[0] = f2bf(v.x); d[1] = f2bf(v.y); d[2] = f2bf(v.z); d[3] = f2bf(v.w);
        }
    }
}

// stage y0 (bf16) with fused BN0-apply + ReLU
__device__ __forceinline__ void stage_y0p(const u16* y0, long first_row,
                                          u16* lds, int stride,
                                          const float* __restrict__ sc,
                                          const float* __restrict__ sh,
                                          int n, int tid) {
#pragma unroll
    for (int i = 0; i < 4; ++i) {
        int s = tid + i * 256;
        int row = s >> 4, within = s & 15;
        long rg = first_row + row; if (rg > n - 1) rg = n - 1;
        short8 v = *(const short8*)(y0 + rg * COUT + within * 8);
        int c = within * 8;
        short8 o;
#pragma unroll
        for (int j = 0; j < 8; ++j)
            o[j] = (short)f2bf(fmaxf(bf2f((u16)v[j]) * sc[c + j] + sh[c + j], 0.f));
        *(short8*)(lds + row * stride + within * 8) = o;
    }
}

// ---------------- dtype detection ----------------
__global__ void k_detect(const unsigned int* __restrict__ x, int* __restrict__ flag) {
    int lane = threadIdx.x;  // 64
    int cnt = 0;
#pragma unroll
    for (int i = 0; i < 8; ++i) {
        unsigned int w = x[lane * 8 + i];
        unsigned int e0 = (w >> 7) & 0xFFu, e1 = (w >> 23) & 0xFFu;
        cnt += (e0 >= 0x60u && e0 <= 0x8Eu);
        cnt += (e1 >= 0x60u && e1 <= 0x8Eu);
    }
    for (int o = 32; o; o >>= 1) cnt += __shfl_down(cnt, o);
    if (lane == 0) *flag = (cnt > 850) ? 1 : 0;   // 1 => bf16
}

// ---------------- partition build (partition = dst >> PSH) ----------------
__global__ __launch_bounds__(256) void k_phist(const int* __restrict__ dst,
                                               int* __restrict__ pcount, int E, int np) {
    __shared__ int h[MAXP];
    for (int i = threadIdx.x; i < np; i += 256) h[i] = 0;
    __syncthreads();
    int stride = gridDim.x * 256;
    for (int e = blockIdx.x * 256 + threadIdx.x; e < E; e += stride)
        atomicAdd(&h[dst[e] >> PSH], 1);
    __syncthreads();
    for (int i = threadIdx.x; i < np; i += 256)
        if (h[i]) atomicAdd(&pcount[i], h[i]);
}

__global__ void k_pscan(const int* __restrict__ pcount, int* __restrict__ pstart,
                        int* __restrict__ pcursor, int np, int E) {
    __shared__ int s[MAXP];
    int t = threadIdx.x;  // 128 threads
    int v = (t < np) ? pcount[t] : 0;
    s[t] = v; __syncthreads();
    for (int o = 1; o < MAXP; o <<= 1) {
        int u = (t >= o) ? s[t - o] : 0;
        __syncthreads(); s[t] += u; __syncthreads();
    }
    if (t < np) {
        int ex = s[t] - v;
        pstart[t] = ex;
        pcursor[t * CURPAD] = ex;
    }
    if (t == 0) pstart[np] = E;
}

// One 4096-edge tile per block. Per-(block,partition) contiguous runs ->
// each barr cache line written by ~one block (no cross-block false sharing).
// rec = (dst & (PNODES-1)) << 20 | src   (src < 2^20)
__global__ __launch_bounds__(256) void k_pfill(const int* __restrict__ src,
        const int* __restrict__ dst, int* __restrict__ pcursor,
        unsigned int* __restrict__ barr, int E, int np) {
    __shared__ int cnt[MAXP], gb[MAXP], loc[MAXP];
    int tid = threadIdx.x;
    int base = blockIdx.x * 4096;
    for (int i = tid; i < np; i += 256) { cnt[i] = 0; loc[i] = 0; }
    __syncthreads();
    int pk[16]; unsigned int rec[16];
#pragma unroll
    for (int k = 0; k < 16; ++k) {
        int e = base + k * 256 + tid;
        if (e < E) {
            int d = dst[e];
            pk[k] = d >> PSH;
            rec[k] = ((unsigned int)(d & (PNODES - 1)) << 20) | (unsigned int)src[e];
            atomicAdd(&cnt[pk[k]], 1);
        } else pk[k] = -1;
    }
    __syncthreads();
    for (int i = tid; i < np; i += 256)
        if (cnt[i]) gb[i] = atomicAdd(&pcursor[i * CURPAD], cnt[i]);
    __syncthreads();
#pragma unroll
    for (int k = 0; k < 16; ++k) {
        if (pk[k] >= 0) {
            int off = atomicAdd(&loc[pk[k]], 1);
            barr[gb[pk[k]] + off] = rec[k];
        }
    }
}

// Block per partition: LDS counting sort -> node-sorted csr + row_start.
__global__ __launch_bounds__(256) void k_psort(const unsigned int* __restrict__ barr,
        const int* __restrict__ pstart, int* __restrict__ csr,
        int* __restrict__ row_start, int n, int np, int E) {
    __shared__ int hist[PNODES], curs[PNODES], tsum[256];
    int tid = threadIdx.x;
    int p = blockIdx.x;
    int e0 = pstart[p], e1 = pstart[p + 1];
    int node0 = p << PSH;
#pragma unroll
    for (int j = 0; j < PNODES / 256; ++j) hist[tid + j * 256] = 0;
    __syncthreads();
    for (int t = e0 + tid; t < e1; t += 256)
        atomicAdd(&hist[barr[t] >> 20], 1);
    __syncthreads();
    // block scan over PNODES=1024 entries (4 per thread)
    int s0 = hist[tid * 4], s1 = hist[tid * 4 + 1], s2 = hist[tid * 4 + 2], s3 = hist[tid * 4 + 3];
    int sum4 = s0 + s1 + s2 + s3;
    tsum[tid] = sum4; __syncthreads();
    for (int o = 1; o < 256; o <<= 1) {
        int u = (tid >= o) ? tsum[tid - o] : 0;
        __syncthreads(); tsum[tid] += u; __syncthreads();
    }
    int bexc = tsum[tid] - sum4;
    int off0 = bexc, off1 = bexc + s0, off2 = off1 + s1, off3 = off2 + s2;
    curs[tid * 4] = off0; curs[tid * 4 + 1] = off1;
    curs[tid * 4 + 2] = off2; curs[tid * 4 + 3] = off3;
    int nd = node0 + tid * 4;
    if (nd < n)     row_start[nd]     = e0 + off0;
    if (nd + 1 < n) row_start[nd + 1] = e0 + off1;
    if (nd + 2 < n) row_start[nd + 2] = e0 + off2;
    if (nd + 3 < n) row_start[nd + 3] = e0 + off3;
    if (p == np - 1 && tid == 0) row_start[n] = E;
    __syncthreads();
    for (int t = e0 + tid; t < e1; t += 256) {
        unsigned int rec = barr[t];
        int pos = atomicAdd(&curs[rec >> 20], 1);
        csr[e0 + pos] = (int)(rec & 0xFFFFF);
    }
}

// ---------------- aggregation (pull, wave per node, coalesced rows) -------
template<bool BF>
__device__ __forceinline__ void agg0_impl(const void* x, const int* rs, const int* csr,
                                          u16* agg, int n) {
    int i = blockIdx.x * 4 + (threadIdx.x >> 6);
    if (i >= n) return;
    int lane = threadIdx.x & 63;
    int h = lane >> 5, cp = lane & 31;
    int b = rs[i], e = rs[i + 1];
    float a0 = 0.f, a1 = 0.f, b0 = 0.f, b1 = 0.f;
    int t = b + h;
    for (; t + 2 < e; t += 4) {
        int j0 = csr[t], j1 = csr[t + 2];
        if (BF) {
            unsigned int w0 = ((const unsigned int*)x)[(long)j0 * 32 + cp];
            unsigned int w1 = ((const unsigned int*)x)[(long)j1 * 32 + cp];
            a0 += lo16(w0); a1 += hi16(w0);
            b0 += lo16(w1); b1 += hi16(w1);
        } else {
            float2 w0 = ((const float2*)x)[(long)j0 * 32 + cp];
            float2 w1 = ((const float2*)x)[(long)j1 * 32 + cp];
            a0 += w0.x; a1 += w0.y;
            b0 += w1.x; b1 += w1.y;
        }
    }
    for (; t < e; t += 2) {
        int j0 = csr[t];
        if (BF) {
            unsigned int w0 = ((const unsigned int*)x)[(long)j0 * 32 + cp];
            a0 += lo16(w0); a1 += hi16(w0);
        } else {
            float2 w0 = ((const float2*)x)[(long)j0 * 32 + cp];
            a0 += w0.x; a1 += w0.y;
        }
    }
    a0 += b0; a1 += b1;
    a0 += __shfl_xor(a0, 32);
    a1 += __shfl_xor(a1, 32);
    if (h == 0) {
        unsigned int o = (unsigned int)f2bf(a0) | ((unsigned int)f2bf(a1) << 16);
        ((unsigned int*)agg)[(long)i * 32 + cp] = o;
    }
}

__global__ __launch_bounds__(256) void k_agg0(const int* __restrict__ flag,
        const void* x, const int* __restrict__ rs, const int* __restrict__ csr,
        u16* __restrict__ agg, int n) {
    if (*flag) agg0_impl<true >(x, rs, csr, agg, n);
    else       agg0_impl<false>(x, rs, csr, agg, n);
}

// agg1: gathers relu(bn0(y0_raw)); scale/shift applied on the fly. bf16 internal.
__global__ __launch_bounds__(256) void k_agg1(const u16* __restrict__ y0,
        const int* __restrict__ rs, const int* __restrict__ csr,
        const float* __restrict__ scale, const float* __restrict__ shift,
        u16* __restrict__ agg, int n) {
    int i = blockIdx.x * 4 + (threadIdx.x >> 6);
    if (i >= n) return;
    int lane = threadIdx.x & 63;
    int c0 = 2 * lane;
    float s0 = scale[c0], s1 = scale[c0 + 1];
    float h0 = shift[c0], h1 = shift[c0 + 1];
    const unsigned int* y32 = (const unsigned int*)y0;
    int b = rs[i], e = rs[i + 1];
    float a0 = 0.f, a1 = 0.f, b0 = 0.f, b1 = 0.f;
    float c0a = 0.f, c1a = 0.f, d0 = 0.f, d1 = 0.f;
    int t = b;
    for (; t + 4 <= e; t += 4) {
        int j0 = csr[t], j1 = csr[t + 1], j2 = csr[t + 2], j3 = csr[t + 3];
        unsigned int w0 = y32[(long)j0 * 64 + lane];
        unsigned int w1 = y32[(long)j1 * 64 + lane];
        unsigned int w2 = y32[(long)j2 * 64 + lane];
        unsigned int w3 = y32[(long)j3 * 64 + lane];
        a0  += fmaxf(lo16(w0) * s0 + h0, 0.f); a1  += fmaxf(hi16(w0) * s1 + h1, 0.f);
        b0  += fmaxf(lo16(w1) * s0 + h0, 0.f); b1  += fmaxf(hi16(w1) * s1 + h1, 0.f);
        c0a += fmaxf(lo16(w2) * s0 + h0, 0.f); c1a += fmaxf(hi16(w2) * s1 + h1, 0.f);
        d0  += fmaxf(lo16(w3) * s0 + h0, 0.f); d1  += fmaxf(hi16(w3) * s1 + h1, 0.f);
    }
    for (; t < e; ++t) {
        unsigned int w0 = y32[(long)csr[t] * 64 + lane];
        a0 += fmaxf(lo16(w0) * s0 + h0, 0.f); a1 += fmaxf(hi16(w0) * s1 + h1, 0.f);
    }
    float s0t = (a0 + b0) + (c0a + d0);
    float s1t = (a1 + b1) + (c1a + d1);
    ((unsigned int*)agg)[(long)i * 64 + lane] =
        (unsigned int)f2bf(s0t) | ((unsigned int)f2bf(s1t) << 16);
}

// ---------------- GEMM0: y0 = [x|agg0] @ [Wr0;Wn0]^T, fused stats ----------
template<bool BF>
__device__ __forceinline__ void gemm0_impl(const void* x, const u16* agg,
                                           const void* Wr, const void* Wn,
                                           u16* y0, float* sum, float* sumsq,
                                           int n, u16* lds) {
    const int ST = 130;
    int tid = threadIdx.x;
    int wave = tid >> 6, lane = tid & 63, lr = lane & 15, q = lane >> 4;
    long chunk0 = (long)blockIdx.x * 64;

    short8 wf[2][4];
#pragma unroll
    for (int i = 0; i < 2; ++i) {
        int c = (2 * wave + i) * 16 + lr;
#pragma unroll
        for (int ks = 0; ks < 4; ++ks) {
            const void* W = (ks < 2) ? Wr : Wn;
            wf[i][ks] = ld8<BF>(W, (long)c * CIN + (ks & 1) * 32 + q * 8);
        }
    }
    stage_tile<BF, 64>(x, chunk0, lds, ST, 0, n, tid);
    stage_tile<true, 64>(agg, chunk0, lds, ST, 64, n, tid);
    __syncthreads();

    float st[2] = {0.f, 0.f}, sq[2] = {0.f, 0.f};
#pragma unroll
    for (int t = 0; t < 4; ++t) {
        short8 a[4];
#pragma unroll
        for (int ks = 0; ks < 4; ++ks)
            a[ks] = *(const short8*)(lds + (t * 16 + lr) * ST + ks * 32 + q * 8);
#pragma unroll
        for (int i = 0; i < 2; ++i) {
            f32x4 acc = {0.f, 0.f, 0.f, 0.f};
#pragma unroll
            for (int ks = 0; ks < 4; ++ks)
                acc = __builtin_amdgcn_mfma_f32_16x16x32_bf16(a[ks], wf[i][ks], acc, 0, 0, 0);
            int c = (2 * wave + i) * 16 + lr;
#pragma unroll
            for (int r = 0; r < 4; ++r) {
                long row = chunk0 + t * 16 + q * 4 + r;
                if (row < n) {
                    y0[row * COUT + c] = f2bf(acc[r]);   // b0 cancels in BN
                    st[i] += acc[r]; sq[i] += acc[r] * acc[r];
                }
            }
        }
    }
#pragma unroll
    for (int i = 0; i < 2; ++i) {
        st[i] += __shfl_xor(st[i], 16); st[i] += __shfl_xor(st[i], 32);
        sq[i] += __shfl_xor(sq[i], 16); sq[i] += __shfl_xor(sq[i], 32);
    }
    if (q == 0) {
#pragma unroll
        for (int i = 0; i < 2; ++i) {
            int c = (2 * wave + i) * 16 + lr;
            atomicAdd(&sum[c], st[i]);
            atomicAdd(&sumsq[c], sq[i]);
        }
    }
}

__global__ __launch_bounds__(256) void k_gemm0(const int* __restrict__ flag,
        const void* x, const u16* __restrict__ agg, const void* Wr, const void* Wn,
        u16* __restrict__ y0, float* __restrict__ sum, float* __restrict__ sumsq, int n) {
    __shared__ u16 lds[64 * 130];
    if (*flag) gemm0_impl<true >(x, agg, Wr, Wn, y0, sum, sumsq, n, lds);
    else       gemm0_impl<false>(x, agg, Wr, Wn, y0, sum, sumsq, n, lds);
}

// ---------------- GEMM1: y1 = [relu(bn0(y0))|agg1] @ [Wr1;Wn1]^T, stats ----
template<bool BF>
__device__ __forceinline__ void gemm1_impl(const u16* y0, const u16* agg,
                                           const void* Wr, const void* Wn,
                                           const float* sc0, const float* sh0,
                                           u16* y1, float* sum, float* sumsq,
                                           int n, u16* lds) {
    const int ST = 258;
    int tid = threadIdx.x;
    int wave = tid >> 6, lane = tid & 63, lr = lane & 15, q = lane >> 4;
    long chunk0 = (long)blockIdx.x * 64;

    short8 wf[2][8];
#pragma unroll
    for (int i = 0; i < 2; ++i) {
        int c = (2 * wave + i) * 16 + lr;
#pragma unroll
        for (int ks = 0; ks < 8; ++ks) {
            const void* W = (ks < 4) ? Wr : Wn;
            wf[i][ks] = ld8<BF>(W, (long)c * COUT + (ks & 3) * 32 + q * 8);
        }
    }
    stage_y0p(y0, chunk0, lds, ST, sc0, sh0, n, tid);
    stage_tile<true, 128>(agg, chunk0, lds, ST, 128, n, tid);
    __syncthreads();

    float st[2] = {0.f, 0.f}, sq[2] = {0.f, 0.f};
#pragma unroll
    for (int t = 0; t < 4; ++t) {
        short8 a[8];
#pragma unroll
        for (int ks = 0; ks < 8; ++ks)
            a[ks] = *(const short8*)(lds + (t * 16 + lr) * ST + ks * 32 + q * 8);
#pragma unroll
        for (int i = 0; i < 2; ++i) {
            f32x4 acc = {0.f, 0.f, 0.f, 0.f};
#pragma unroll
            for (int ks = 0; ks < 8; ++ks)
                acc = __builtin_amdgcn_mfma_f32_16x16x32_bf16(a[ks], wf[i][ks], acc, 0, 0, 0);
            int c = (2 * wave + i) * 16 + lr;
#pragma unroll
            for (int r = 0; r < 4; ++r) {
                long row = chunk0 + t * 16 + q * 4 + r;
                if (row < n) {
                    y1[row * COUT + c] = f2bf(acc[r]);   // b1 cancels in BN
                    st[i] += acc[r]; sq[i] += acc[r] * acc[r];
                }
            }
        }
    }
#pragma unroll
    for (int i = 0; i < 2; ++i) {
        st[i] += __shfl_xor(st[i], 16); st[i] += __shfl_xor(st[i], 32);
        sq[i] += __shfl_xor(sq[i], 16); sq[i] += __shfl_xor(sq[i], 32);
    }
    if (q == 0) {
#pragma unroll
        for (int i = 0; i < 2; ++i) {
            int c = (2 * wave + i) * 16 + lr;
            atomicAdd(&sum[c], st[i]);
            atomicAdd(&sumsq[c], sq[i]);
        }
    }
}

__global__ __launch_bounds__(256) void k_gemm1(const int* __restrict__ flag,
        const u16* __restrict__ y0, const u16* __restrict__ agg,
        const void* Wr, const void* Wn,
        const float* __restrict__ sc0, const float* __restrict__ sh0,
        u16* y1_bf /*=d_out*/, u16* y1_ws,
        float* __restrict__ sum, float* __restrict__ sumsq, int n) {
    __shared__ u16 lds[64 * 258];
    u16* y1 = *flag ? y1_bf : y1_ws;
    if (*flag) gemm1_impl<true >(y0, agg, Wr, Wn, sc0, sh0, y1, sum, sumsq, n, lds);
    else       gemm1_impl<false>(y0, agg, Wr, Wn, sc0, sh0, y1, sum, sumsq, n, lds);
}

// ---------------- BN finalize ----------------
__global__ void k_bnfin(const int* __restrict__ flag,
                        const float* __restrict__ sum, const float* __restrict__ sumsq,
                        const void* g, const void* be,
                        float* __restrict__ scale, float* __restrict__ shift, int n) {
    int c = threadIdx.x;
    bool bf = (*flag != 0);
    float inv = 1.f / (float)n;
    float mu = sum[c] * inv;
    float var = fmaxf(sumsq[c] * inv - mu * mu, 0.f);
    float gv = bf ? bf2f(((const u16*)g)[c]) : ((const float*)g)[c];
    float bv = bf ? bf2f(((const u16*)be)[c]) : ((const float*)be)[c];
    float sc = gv * rsqrtf(var + BN_EPS);
    scale[c] = sc;
    shift[c] = bv - mu * sc;
}

// ---------------- final: out = relu(bn1(y1) + x@Wlin^T + blin) ------------
template<bool BF>
__device__ __forceinline__ void final_impl(const void* x, const u16* y1,
                                           const void* Wlin, const void* blin,
                                           const float* sc, const float* sh,
                                           void* out, int n, u16* lds) {
    const int ST = 194;
    int tid = threadIdx.x;
    int wave = tid >> 6, lane = tid & 63, lr = lane & 15, q = lane >> 4;
    long chunk0 = (long)blockIdx.x * 64;

    short8 wf[2][2];
    float blc[2], scc[2], shc[2];
#pragma unroll
    for (int i = 0; i < 2; ++i) {
        int c = (2 * wave + i) * 16 + lr;
#pragma unroll
        for (int ks = 0; ks < 2; ++ks)
            wf[i][ks] = ld8<BF>(Wlin, (long)c * CIN + ks * 32 + q * 8);
        blc[i] = ldf<BF>(blin, c);
        scc[i] = sc[c]; shc[i] = sh[c];
    }
    stage_tile<BF, 64>(x, chunk0, lds, ST, 0, n, tid);
    stage_tile<true, 128>(y1, chunk0, lds, ST, 64, n, tid);
    __syncthreads();

#pragma unroll
    for (int t = 0; t < 4; ++t) {
        short8 a[2];
#pragma unroll
        for (int ks = 0; ks < 2; ++ks)
            a[ks] = *(const short8*)(lds + (t * 16 + lr) * ST + ks * 32 + q * 8);
#pragma unroll
        for (int i = 0; i < 2; ++i) {
            f32x4 acc = {0.f, 0.f, 0.f, 0.f};
            acc = __builtin_amdgcn_mfma_f32_16x16x32_bf16(a[0], wf[i][0], acc, 0, 0, 0);
            acc = __builtin_amdgcn_mfma_f32_16x16x32_bf16(a[1], wf[i][1], acc, 0, 0, 0);
            int c = (2 * wave + i) * 16 + lr;
#pragma unroll
            for (int r = 0; r < 4; ++r) {
                long row = chunk0 + t * 16 + q * 4 + r;
                if (row < n) {
                    float yv = bf2f(lds[(t * 16 + q * 4 + r) * ST + 64 + c]);
                    float v = acc[r] + blc[i] + yv * scc[i] + shc[i];
                    v = fmaxf(v, 0.f);
                    if (BF) ((u16*)out)[row * COUT + c] = f2bf(v);
                    else    ((float*)out)[row * COUT + c] = v;
                }
            }
        }
    }
}

__global__ __launch_bounds__(256) void k_final(const int* __restrict__ flag,
        const void* x, const void* Wlin, const void* blin,
        const u16* y1_bf /*=d_out*/, const u16* y1_ws,
        const float* __restrict__ sc, const float* __restrict__ sh,
        void* out, int n) {
    __shared__ u16 lds[64 * 194];
    const u16* y1 = *flag ? y1_bf : y1_ws;
    if (*flag) final_impl<true >(x, y1, Wlin, blin, sc, sh, out, n, lds);
    else       final_impl<false>(x, y1, Wlin, blin, sc, sh, out, n, lds);
}

extern "C" void kernel_launch(void* const* d_in, const int* in_sizes, int n_in,
                              void* d_out, int out_size, void* d_ws, size_t ws_size,
                              hipStream_t stream) {
    (void)n_in; (void)out_size; (void)ws_size;
    const void* x    = d_in[0];
    const int*  ei   = (const int*)d_in[1];
    const void* Wr0  = d_in[2];
    const void* Wn0  = d_in[3];
    /* b0 dropped: BN-invariant */
    const void* g0   = d_in[5];
    const void* be0  = d_in[6];
    const void* Wr1  = d_in[7];
    const void* Wn1  = d_in[8];
    /* b1 dropped */
    const void* g1   = d_in[10];
    const void* be1  = d_in[11];
    const void* Wlin = d_in[12];
    const void* blin = d_in[13];

    const int N = in_sizes[0] / CIN;
    const int E = in_sizes[1] / 2;
    const int* src = ei;
    const int* dst = ei + E;
    const int NP = (N + PNODES - 1) >> PSH;   // partitions (<= MAXP for N <= 131072)

    // ---- workspace carve (256B aligned); f32-only region LAST ----
    char* base = (char*)d_ws;
    size_t off = 0;
    auto carve = [&](size_t bytes) -> void* {
        void* p = base + off;
        off = (off + bytes + 255) & ~(size_t)255;
        return p;
    };
    int*   flag      = (int*)carve(256);
    int*   pcount    = (int*)carve(MAXP * sizeof(int));
    int*   pstart    = (int*)carve((MAXP + 1) * sizeof(int));
    int*   pcursor   = (int*)carve(MAXP * CURPAD * sizeof(int));
    float* stats     = (float*)carve(512 * sizeof(float));  // sum0,sq0,sum1,sq1
    float* scsh      = (float*)carve(512 * sizeof(float));  // scale0,shift0,scale1,shift1
    int*   row_start = (int*)carve((size_t)(N + 1) * sizeof(int));
    unsigned int* barr = (unsigned int*)carve((size_t)E * sizeof(int));
    int*   csr       = (int*)carve((size_t)E * sizeof(int));
    u16*   aggu      = (u16*)carve((size_t)N * COUT * sizeof(u16)); // agg0 aliases agg1
    u16*   y0        = (u16*)carve((size_t)N * COUT * sizeof(u16));
    u16*   y1_ws     = (u16*)carve((size_t)N * COUT * sizeof(u16)); // f32 mode only

    hipMemsetAsync(pcount, 0, MAXP * sizeof(int), stream);
    hipMemsetAsync(stats, 0, 512 * sizeof(float), stream);

    const int nwb = (N + 3) / 4;        // wave-per-node blocks
    const int nch = (N + 63) / 64;      // 64-row chunks for dense kernels
    const int ntl = (E + 4095) / 4096;  // pfill tiles

    k_detect<<<1, 64, 0, stream>>>((const unsigned int*)x, flag);

    k_phist<<<256, 256, 0, stream>>>(dst, pcount, E, NP);
    k_pscan<<<1, MAXP, 0, stream>>>(pcount, pstart, pcursor, NP, E);
    k_pfill<<<ntl, 256, 0, stream>>>(src, dst, pcursor, barr, E, NP);
    k_psort<<<NP, 256, 0, stream>>>(barr, pstart, csr, row_start, N, NP, E);

    k_agg0 <<<nwb, 256, 0, stream>>>(flag, x, row_start, csr, aggu, N);
    k_gemm0<<<nch, 256, 0, stream>>>(flag, x, aggu, Wr0, Wn0, y0,
                                     stats, stats + 128, N);
    k_bnfin<<<1, 128, 0, stream>>>(flag, stats, stats + 128, g0, be0,
                                   scsh, scsh + 128, N);

    k_agg1 <<<nwb, 256, 0, stream>>>(y0, row_start, csr, scsh, scsh + 128, aggu, N);
    k_gemm1<<<nch, 256, 0, stream>>>(flag, y0, aggu, Wr1, Wn1, scsh, scsh + 128,
                                     (u16*)d_out, y1_ws, stats + 256, stats + 384, N);
    k_bnfin<<<1, 128, 0, stream>>>(flag, stats + 256, stats + 384, g1, be1,
                                   scsh + 256, scsh + 384, N);

    k_final<<<nch, 256, 0, stream>>>(flag, x, Wlin, blin,
                                     (const u16*)d_out, y1_ws,
                                     scsh + 256, scsh + 384, d_out, N);
}